// Round 10
// baseline (170.978 us; speedup 1.0000x reference)
//
#include <hip/hip_runtime.h>
#include <hip/hip_bf16.h>
#include <stdint.h>

typedef __attribute__((ext_vector_type(8))) __bf16 bf16x8;
typedef __attribute__((ext_vector_type(4))) __bf16 bf16x4;
typedef __attribute__((ext_vector_type(4))) float f32x4;

#define QSCALE (0.125f * 1.44269504f)

#define GL16(src, dst) __builtin_amdgcn_global_load_lds( \
    (const __attribute__((address_space(1))) void*)(src), \
    (__attribute__((address_space(3))) void*)(dst), 16, 0, 0)

static __device__ inline unsigned pkbf(float a, float b) {
  __bf16 x = (__bf16)a, y = (__bf16)b;
  unsigned short ux = __builtin_bit_cast(unsigned short, x);
  unsigned short uy = __builtin_bit_cast(unsigned short, y);
  return ((unsigned)uy << 16) | ux;
}

static __device__ inline float ex2(float x) {
#if __has_builtin(__builtin_amdgcn_exp2f)
  return __builtin_amdgcn_exp2f(x);
#else
  float r;
  asm("v_exp_f32 %0, %1" : "=v"(r) : "v"(x));
  return r;
#endif
}

// ---------------- fused prep: cvt + 4x transpose-convert + rope table ----------------
__global__ __launch_bounds__(256) void k_prep(const float* __restrict__ x,
                                              __bf16* __restrict__ xb,
                                              const float* __restrict__ wq,
                                              const float* __restrict__ wk,
                                              const float* __restrict__ wv,
                                              const float* __restrict__ wo,
                                              __bf16* __restrict__ wqkvT,
                                              __bf16* __restrict__ woT,
                                              float* __restrict__ ct,
                                              float* __restrict__ st) {
  int bid = blockIdx.x, tid = threadIdx.x;
  if (bid < 4096) {  // ---- cvt ----
    int i = bid * 256 + tid;
    const float4* p = (const float4*)(x) + (size_t)i * 2;
    float4 a = p[0], b = p[1];
    bf16x8 o;
    o[0] = (__bf16)a.x; o[1] = (__bf16)a.y; o[2] = (__bf16)a.z; o[3] = (__bf16)a.w;
    o[4] = (__bf16)b.x; o[5] = (__bf16)b.y; o[6] = (__bf16)b.z; o[7] = (__bf16)b.w;
    ((bf16x8*)xb)[i] = o;
    return;
  }
  if (bid >= 14336) {  // ---- rope table ----
    int i = (bid - 14336) * 256 + tid;
    int s = i >> 5, j = i & 31;
    float invf = powf(10000.0f, -(float)j / 32.0f);
    float fr = (float)s * invf;
    ct[i] = cosf(fr);
    st[i] = sinf(fr);
    return;
  }
  // ---- transpose-convert ----
  __shared__ float tile[32][33];
  const float* w;
  __bf16* wT;
  int N, r;
  if (bid < 8192)       { r = bid - 4096;  w = wq; wT = wqkvT;                        N = 2048; }
  else if (bid < 9216)  { r = bid - 8192;  w = wk; wT = wqkvT + (size_t)2048 * 2048;  N = 512; }
  else if (bid < 10240) { r = bid - 9216;  w = wv; wT = wqkvT + (size_t)2560 * 2048;  N = 512; }
  else                  { r = bid - 10240; w = wo; wT = woT;                          N = 2048; }
  int ntiles = N >> 5;
  int n0 = (r % ntiles) * 32, k0 = (r / ntiles) * 32;
  int tx = tid & 31, ty = tid >> 5;  // (32,8)
#pragma unroll
  for (int i = 0; i < 32; i += 8)
    tile[ty + i][tx] = w[(size_t)(k0 + ty + i) * N + n0 + tx];
  __syncthreads();
#pragma unroll
  for (int i = 0; i < 32; i += 8)
    wT[(size_t)(n0 + ty + i) * 2048 + k0 + tx] = (__bf16)tile[tx][ty + i];
}

// ---------------- QKV GEMM (round-1 measured-best): 2-deep, deferred af1 ----------------
template <int BN, int NW, int WPN, int MODE>
__global__ __launch_bounds__(NW * 64, NW / 4) void k_gemm256(const __bf16* __restrict__ A,
                                                             const __bf16* __restrict__ BT,
                                                             void* __restrict__ C0,
                                                             __bf16* __restrict__ kb,
                                                             __bf16* __restrict__ vt,
                                                             const float* __restrict__ ct,
                                                             const float* __restrict__ st,
                                                             int K, int NBN) {
  constexpr int WPM = NW / WPN;         // waves along M
  constexpr int MF = 256 / WPM / 16;    // M-frags per wave
  constexpr int NF = BN / WPN / 16;     // N-frags per wave (64 cols)
  constexpr int MH = MF / 2;
  constexpr int CHA = 256 * 8;          // A 16B-chunks per K-tile
  constexpr int CHB = BN * 8;           // B 16B-chunks per K-tile
  constexpr int PA = CHA / (NW * 64);   // full A staging passes
  constexpr int RA = CHA - PA * NW * 64;// A remainder chunks (wave-aligned)
  constexpr int PB = CHB / (NW * 64);   // full B staging passes
  static_assert(CHB % (NW * 64) == 0, "B chunks must tile threads");
  static_assert(RA % 64 == 0, "A remainder must be wave-aligned");
  static_assert(NF == 4, "epilogue assumes 64-col wave window");
  __shared__ __align__(16) __bf16 lA[2][256 * 64];
  __shared__ __align__(16) __bf16 lB[2][BN * 64];
  int bm = (blockIdx.x / NBN) << 8;
  int bn = (blockIdx.x % NBN) * BN;
  int tid = threadIdx.x, l = tid & 63, w = tid >> 6;
  int wr = w / WPN, wc = w % WPN;
  int lrow = l & 15, lk = l >> 4;
  int NT = K >> 6;
  f32x4 acc[MF][NF] = {};

#define STG(T, BUF)                                                           \
  do {                                                                        \
    int k0_ = (T) << 6;                                                       \
    _Pragma("unroll") for (int i_ = 0; i_ < PA; i_++) {                       \
      int ch_ = i_ * (NW * 64) + tid;                                         \
      int r_ = ch_ >> 3, c_ = ch_ & 7;                                        \
      GL16(A + (size_t)(bm + r_) * K + k0_ + ((c_ ^ (r_ & 7)) << 3),          \
           &lA[BUF][(i_ * (NW * 64) + (w << 6)) * 8]);                        \
    }                                                                         \
    if constexpr (RA > 0) {                                                   \
      if (tid < RA) {                                                         \
        int ch_ = PA * (NW * 64) + tid;                                       \
        int r_ = ch_ >> 3, c_ = ch_ & 7;                                      \
        GL16(A + (size_t)(bm + r_) * K + k0_ + ((c_ ^ (r_ & 7)) << 3),        \
             &lA[BUF][(PA * (NW * 64) + (w << 6)) * 8]);                      \
      }                                                                       \
    }                                                                         \
    _Pragma("unroll") for (int i_ = 0; i_ < PB; i_++) {                       \
      int ch_ = i_ * (NW * 64) + tid;                                         \
      int r_ = ch_ >> 3, c_ = ch_ & 7;                                        \
      GL16(BT + (size_t)(bn + r_) * K + k0_ + ((c_ ^ (r_ & 7)) << 3),         \
           &lB[BUF][(i_ * (NW * 64) + (w << 6)) * 8]);                        \
    }                                                                         \
  } while (0)

#define WAITN()                                                               \
  do {                                                                        \
    if constexpr (RA > 0) {                                                   \
      if (w < (RA >> 6))                                                      \
        asm volatile("s_waitcnt vmcnt(%0)" ::"i"(PA + PB + 1) : "memory");    \
      else                                                                    \
        asm volatile("s_waitcnt vmcnt(%0)" ::"i"(PA + PB) : "memory");        \
    } else {                                                                  \
      asm volatile("s_waitcnt vmcnt(%0)" ::"i"(PA + PB) : "memory");          \
    }                                                                         \
  } while (0)

  STG(0, 0);
  STG(1, 1);
  WAITN();
  __builtin_amdgcn_sched_barrier(0);
  __builtin_amdgcn_s_barrier();

  for (int t = 0; t < NT; t++) {
    int buf = t & 1;
    const char* bA = (const char*)lA[buf];
    const char* bB = (const char*)lB[buf];
    bf16x8 bfr[NF][2], af0[MH][2], af1[MH][2];
#pragma unroll
    for (int nf = 0; nf < NF; nf++) {
      int row = wc * (NF * 16) + nf * 16 + lrow;
#pragma unroll
      for (int kc = 0; kc < 2; kc++)
        bfr[nf][kc] = *(const bf16x8*)(bB + row * 128 +
                                       ((kc * 64 + 16 * lk) ^ ((row & 7) << 4)));
    }
#pragma unroll
    for (int mf = 0; mf < MH; mf++) {
      int row = wr * (MF * 16) + mf * 16 + lrow;
#pragma unroll
      for (int kc = 0; kc < 2; kc++)
        af0[mf][kc] = *(const bf16x8*)(bA + row * 128 +
                                       ((kc * 64 + 16 * lk) ^ ((row & 7) << 4)));
    }
    __builtin_amdgcn_s_setprio(1);
#pragma unroll
    for (int kc = 0; kc < 2; kc++)
#pragma unroll
      for (int mf = 0; mf < MH; mf++)
#pragma unroll
        for (int nf = 0; nf < NF; nf++)
          acc[mf][nf] = __builtin_amdgcn_mfma_f32_16x16x32_bf16(af0[mf][kc], bfr[nf][kc],
                                                                acc[mf][nf], 0, 0, 0);
    __builtin_amdgcn_s_setprio(0);
#pragma unroll
    for (int mf = 0; mf < MH; mf++) {
      int row = wr * (MF * 16) + (MH + mf) * 16 + lrow;
#pragma unroll
      for (int kc = 0; kc < 2; kc++)
        af1[mf][kc] = *(const bf16x8*)(bA + row * 128 +
                                       ((kc * 64 + 16 * lk) ^ ((row & 7) << 4)));
    }
    asm volatile("s_waitcnt lgkmcnt(0)" ::: "memory");
    __builtin_amdgcn_sched_barrier(0);
    __builtin_amdgcn_s_barrier();        // all waves done reading buf
    if (t + 2 < NT) STG(t + 2, buf);     // overwrite freed buf, loads fly over MFMA
    __builtin_amdgcn_s_setprio(1);
#pragma unroll
    for (int kc = 0; kc < 2; kc++)
#pragma unroll
      for (int mf = 0; mf < MH; mf++)
#pragma unroll
        for (int nf = 0; nf < NF; nf++)
          acc[MH + mf][nf] = __builtin_amdgcn_mfma_f32_16x16x32_bf16(
              af1[mf][kc], bfr[nf][kc], acc[MH + mf][nf], 0, 0, 0);
    __builtin_amdgcn_s_setprio(0);
    if (t + 2 < NT) {
      WAITN();                           // t+1 ready, t+2 still flying
    } else {
      asm volatile("s_waitcnt vmcnt(0)" ::: "memory");
    }
    __builtin_amdgcn_sched_barrier(0);
    __builtin_amdgcn_s_barrier();
  }
#undef STG
#undef WAITN

  if constexpr (MODE == 0) {
    int wcb = bn + wc * 64;   // wave's 64-col window = one head
    __bf16* qb = (__bf16*)C0;
    if (wcb < 2048) {
#pragma unroll
      for (int mf = 0; mf < MF; mf++)
#pragma unroll
        for (int r = 0; r < 4; r++) {
          int row = bm + wr * (MF * 16) + mf * 16 + 4 * lk + r;
          int sidx = row & 2047;
#pragma unroll
          for (int nfl = 0; nfl < 2; nfl++) {
            int d = nfl * 16 + lrow;
            float c = ct[sidx * 32 + d], sn = st[sidx * 32 + d];
            float a = acc[mf][nfl][r], b2 = acc[mf][nfl + 2][r];
            qb[(size_t)row * 2048 + wcb + d] = (__bf16)((a * c - b2 * sn) * QSCALE);
            qb[(size_t)row * 2048 + wcb + d + 32] = (__bf16)((b2 * c + a * sn) * QSCALE);
          }
        }
    } else if (wcb < 2560) {
      int cb = wcb - 2048;
#pragma unroll
      for (int mf = 0; mf < MF; mf++)
#pragma unroll
        for (int r = 0; r < 4; r++) {
          int row = bm + wr * (MF * 16) + mf * 16 + 4 * lk + r;
          int sidx = row & 2047;
#pragma unroll
          for (int nfl = 0; nfl < 2; nfl++) {
            int d = nfl * 16 + lrow;
            float c = ct[sidx * 32 + d], sn = st[sidx * 32 + d];
            float a = acc[mf][nfl][r], b2 = acc[mf][nfl + 2][r];
            kb[(size_t)row * 512 + cb + d] = (__bf16)(a * c - b2 * sn);
            kb[(size_t)row * 512 + cb + d + 32] = (__bf16)(b2 * c + a * sn);
          }
        }
    } else {
      int hkk = (wcb - 2560) >> 6;
#pragma unroll
      for (int mf = 0; mf < MF; mf++)
#pragma unroll
        for (int nf = 0; nf < NF; nf++)
#pragma unroll
          for (int r = 0; r < 4; r++) {
            int row = bm + wr * (MF * 16) + mf * 16 + 4 * lk + r;
            int dd = nf * 16 + lrow;
            int bb = row >> 11, s = row & 2047;
            vt[(size_t)(((bb << 3) + hkk) * 64 + dd) * 2048 + s] = (__bf16)acc[mf][nf][r];
          }
    }
  } else {
    float* C = (float*)C0;
#pragma unroll
    for (int mf = 0; mf < MF; mf++)
#pragma unroll
      for (int nf = 0; nf < NF; nf++)
#pragma unroll
        for (int r = 0; r < 4; r++) {
          int row = bm + wr * (MF * 16) + mf * 16 + 4 * lk + r;
          int col = bn + wc * 64 + nf * 16 + lrow;
          C[(size_t)row * 2048 + col] = acc[mf][nf][r];
        }
  }
}

// ---------------- WO GEMM (round-2 measured-best): 3-deep A, upfront reads, swizzle ----
template <int BN, int NW, int WPN, int MODE>
__global__ __launch_bounds__(NW * 64, NW / 4) void k_gemm3d(const __bf16* __restrict__ A,
                                                            const __bf16* __restrict__ BT,
                                                            void* __restrict__ C0,
                                                            int K, int NBN) {
  constexpr int WPM = NW / WPN;
  constexpr int MF = 256 / WPM / 16;
  constexpr int NF = BN / WPN / 16;
  constexpr int MH = MF / 2;
  constexpr int CHA = 256 * 8;
  constexpr int CHB = BN * 8;
  constexpr int PA = CHA / (NW * 64);
  constexpr int RA = CHA - PA * NW * 64;
  constexpr int PB = CHB / (NW * 64);
  static_assert(CHB % (NW * 64) == 0, "B chunks must tile threads");
  static_assert(RA % 64 == 0, "A remainder must be wave-aligned");
  static_assert(NF == 4, "wave owns a 64-col window");
  constexpr int LB = PB;
  constexpr int LA0 = PA + (RA > 0 ? 1 : 0);
  constexpr int LA1 = PA;
  constexpr int NS0 = 2 * LA0 + LB, NS1 = 2 * LA1 + LB;
  constexpr int NM0 = LA0 + LB, NM1 = LA1 + LB;
  __shared__ __align__(16) __bf16 lA[3][256 * 64];
  __shared__ __align__(16) __bf16 lB[2][BN * 64];
  int bid = blockIdx.x;
  int lg = (bid & 7) * ((int)gridDim.x >> 3) + (bid >> 3);
  int bm = (lg / NBN) << 8;
  int bn = (lg % NBN) * BN;
  int tid = threadIdx.x, l = tid & 63, w = tid >> 6;
  int wr = w / WPN, wc = w % WPN;
  int lrow = l & 15, lk = l >> 4;
  int NT = K >> 6;
  f32x4 acc[MF][NF] = {};

#define STGA(T, BUF)                                                          \
  do {                                                                        \
    int k0_ = (T) << 6;                                                       \
    _Pragma("unroll") for (int i_ = 0; i_ < PA; i_++) {                       \
      int ch_ = i_ * (NW * 64) + tid;                                         \
      int r_ = ch_ >> 3, c_ = ch_ & 7;                                        \
      GL16(A + (size_t)(bm + r_) * K + k0_ + ((c_ ^ (r_ & 7)) << 3),          \
           &lA[BUF][(i_ * (NW * 64) + (w << 6)) * 8]);                        \
    }                                                                         \
    if constexpr (RA > 0) {                                                   \
      if (tid < RA) {                                                         \
        int ch_ = PA * (NW * 64) + tid;                                       \
        int r_ = ch_ >> 3, c_ = ch_ & 7;                                      \
        GL16(A + (size_t)(bm + r_) * K + k0_ + ((c_ ^ (r_ & 7)) << 3),        \
             &lA[BUF][(PA * (NW * 64) + (w << 6)) * 8]);                      \
      }                                                                       \
    }                                                                         \
  } while (0)

#define STGB(T, BUF)                                                          \
  do {                                                                        \
    int k0_ = (T) << 6;                                                       \
    _Pragma("unroll") for (int i_ = 0; i_ < PB; i_++) {                       \
      int ch_ = i_ * (NW * 64) + tid;                                         \
      int r_ = ch_ >> 3, c_ = ch_ & 7;                                        \
      GL16(BT + (size_t)(bn + r_) * K + k0_ + ((c_ ^ (r_ & 7)) << 3),         \
           &lB[BUF][(i_ * (NW * 64) + (w << 6)) * 8]);                        \
    }                                                                         \
  } while (0)

#define WAIT_STEADY()                                                         \
  do {                                                                        \
    if constexpr (RA > 0) {                                                   \
      if (w < (RA >> 6))                                                      \
        asm volatile("s_waitcnt vmcnt(%0)" ::"i"(NS0) : "memory");            \
      else                                                                    \
        asm volatile("s_waitcnt vmcnt(%0)" ::"i"(NS1) : "memory");            \
    } else {                                                                  \
      asm volatile("s_waitcnt vmcnt(%0)" ::"i"(NS1) : "memory");              \
    }                                                                         \
  } while (0)

#define WAIT_MID()                                                            \
  do {                                                                        \
    if constexpr (RA > 0) {                                                   \
      if (w < (RA >> 6))                                                      \
        asm volatile("s_waitcnt vmcnt(%0)" ::"i"(NM0) : "memory");            \
      else                                                                    \
        asm volatile("s_waitcnt vmcnt(%0)" ::"i"(NM1) : "memory");            \
    } else {                                                                  \
      asm volatile("s_waitcnt vmcnt(%0)" ::"i"(NM1) : "memory");              \
    }                                                                         \
  } while (0)

  STGB(0, 0); STGA(0, 0);
  STGB(1, 1); STGA(1, 1);
  STGA(2, 2);
  WAIT_STEADY();
  __builtin_amdgcn_sched_barrier(0);
  __builtin_amdgcn_s_barrier();

  int a0 = 0;
  for (int t = 0; t < NT; t++) {
    const char* bA = (const char*)lA[a0];
    const char* bB = (const char*)lB[t & 1];
    bf16x8 bfr[NF][2], af0[MH][2], af1[MH][2];
#pragma unroll
    for (int nf = 0; nf < NF; nf++) {
      int row = wc * (NF * 16) + nf * 16 + lrow;
#pragma unroll
      for (int kc = 0; kc < 2; kc++)
        bfr[nf][kc] = *(const bf16x8*)(bB + row * 128 +
                                       ((kc * 64 + 16 * lk) ^ ((row & 7) << 4)));
    }
#pragma unroll
    for (int mf = 0; mf < MH; mf++) {
      int row = wr * (MF * 16) + mf * 16 + lrow;
#pragma unroll
      for (int kc = 0; kc < 2; kc++)
        af0[mf][kc] = *(const bf16x8*)(bA + row * 128 +
                                       ((kc * 64 + 16 * lk) ^ ((row & 7) << 4)));
    }
#pragma unroll
    for (int mf = 0; mf < MH; mf++) {
      int row = wr * (MF * 16) + (MH + mf) * 16 + lrow;
#pragma unroll
      for (int kc = 0; kc < 2; kc++)
        af1[mf][kc] = *(const bf16x8*)(bA + row * 128 +
                                       ((kc * 64 + 16 * lk) ^ ((row & 7) << 4)));
    }
    __builtin_amdgcn_s_setprio(1);
#pragma unroll
    for (int kc = 0; kc < 2; kc++)
#pragma unroll
      for (int mf = 0; mf < MH; mf++)
#pragma unroll
        for (int nf = 0; nf < NF; nf++)
          acc[mf][nf] = __builtin_amdgcn_mfma_f32_16x16x32_bf16(af0[mf][kc], bfr[nf][kc],
                                                                acc[mf][nf], 0, 0, 0);
    __builtin_amdgcn_s_setprio(0);
    asm volatile("s_waitcnt lgkmcnt(0)" ::: "memory");
    __builtin_amdgcn_sched_barrier(0);
    __builtin_amdgcn_s_barrier();
    if (t + 2 < NT) STGB(t + 2, t & 1);
    if (t + 3 < NT) STGA(t + 3, a0);
    __builtin_amdgcn_s_setprio(1);
#pragma unroll
    for (int kc = 0; kc < 2; kc++)
#pragma unroll
      for (int mf = 0; mf < MH; mf++)
#pragma unroll
        for (int nf = 0; nf < NF; nf++)
          acc[MH + mf][nf] = __builtin_amdgcn_mfma_f32_16x16x32_bf16(
              af1[mf][kc], bfr[nf][kc], acc[MH + mf][nf], 0, 0, 0);
    __builtin_amdgcn_s_setprio(0);
    if (t + 3 < NT) {
      WAIT_STEADY();
    } else if (t + 2 < NT) {
      WAIT_MID();
    } else if (t + 1 < NT) {
      asm volatile("s_waitcnt vmcnt(0)" ::: "memory");
    }
    __builtin_amdgcn_sched_barrier(0);
    __builtin_amdgcn_s_barrier();
    a0 = (a0 == 2) ? 0 : a0 + 1;
  }
#undef STGA
#undef STGB
#undef WAIT_STEADY
#undef WAIT_MID

  float* C = (float*)C0;
#pragma unroll
  for (int mf = 0; mf < MF; mf++)
#pragma unroll
    for (int nf = 0; nf < NF; nf++)
#pragma unroll
      for (int r = 0; r < 4; r++) {
        int row = bm + wr * (MF * 16) + mf * 16 + 4 * lk + r;
        int col = bn + wc * 64 + nf * 16 + lrow;
        C[(size_t)row * 2048 + col] = acc[mf][nf][r];
      }
}

// ---------------- causal GQA flash attention v6: T15 P-pipeline ----------------
// v4c structure (QBLK=32, grid 1024, descending-c) with one-tile P-state carry:
// at step t, QK(t)->sCur runs while softmax+PV of sPrev(t-1) executes — the
// softmax VALU is independent of QK(t)'s MFMAs, so the two pipes interleave
// (T15, +7-11% measured on attn). Consequences: PV reads V one tile late ->
// V triple-buffered, K double-buffered (stage distance 1, issue order K,K,V,V;
// per-step vmcnt(2) drains K(t)+V(t-1), leaves V(t) flying). Static even/odd
// unroll keeps sA/sB register-indexed (rule #20). LDS 40KB.
__global__ __launch_bounds__(256, 3) void k_attn(const __bf16* __restrict__ Q,
                                                 const __bf16* __restrict__ Kb,
                                                 const __bf16* __restrict__ VT,
                                                 __bf16* __restrict__ O) {
  __shared__ __align__(16) __bf16 lK[2][64 * 64];
  __shared__ __align__(16) __bf16 lV[3][64 * 64];
  int bid = blockIdx.x;            // 1024
  int c = 63 - (bid >> 4);         // q-chunk of 32 rows, most work first
  int hk = bid & 7;
  int b = (bid >> 3) & 1;
  int tid = threadIdx.x, l = tid & 63, w = tid >> 6;
  int h = hk * 4 + w;
  int lrow = l & 15, lk = l >> 4;
  int sw = (lrow & 7) << 4;
  int tl = c >> 1;                 // last kv tile index

#define STAGEK(BUF, T)                                                                    \
  do {                                                                                    \
    int kv0_ = (T) * 64;                                                                  \
    _Pragma("unroll") for (int i_ = 0; i_ < 2; i_++) {                                    \
      int cb_ = i_ * 256 + w * 64;                                                        \
      int chunk_ = cb_ + l;                                                               \
      int row_ = chunk_ >> 3, cc_ = chunk_ & 7;                                           \
      GL16(Kb + (size_t)(b * 2048 + kv0_ + row_) * 512 + hk * 64 +                        \
               ((cc_ ^ (row_ & 7)) << 3),                                                 \
           &lK[BUF][cb_ * 8]);                                                            \
    }                                                                                     \
  } while (0)

#define STAGEV(BUF, T)                                                                    \
  do {                                                                                    \
    int kv0_ = (T) * 64;                                                                  \
    _Pragma("unroll") for (int i_ = 0; i_ < 2; i_++) {                                    \
      int cb_ = i_ * 256 + w * 64;                                                        \
      int chunk_ = cb_ + l;                                                               \
      int row_ = chunk_ >> 3, cc_ = chunk_ & 7;                                           \
      GL16(VT + (size_t)((b * 8 + hk) * 64 + row_) * 2048 + kv0_ +                        \
               ((cc_ ^ (row_ & 7)) << 3),                                                 \
           &lV[BUF][cb_ * 8]);                                                            \
    }                                                                                     \
  } while (0)

  // Q fragments: 2 q-frags x 2 k-chunks, live in registers for the whole pass
  bf16x8 aq[2][2];
#pragma unroll
  for (int qf = 0; qf < 2; qf++) {
    int qrow = c * 32 + qf * 16 + lrow;
    const __bf16* qp = Q + (size_t)(b * 2048 + qrow) * 2048 + h * 64 + lk * 8;
    aq[qf][0] = *(const bf16x8*)qp;
    aq[qf][1] = *(const bf16x8*)(qp + 32);
  }
  f32x4 o[2][4] = {};
  float lp[2] = {0.f, 0.f};
  f32x4 sA[2][4], sB[2][4];

// swapped QK^T into SC: SC[qf][nf][r] = P^T[kv = nf*16+4*lk+r][q = lrow]
#define QKS(T, SC)                                                                        \
  do {                                                                                    \
    const char* K_ = (const char*)lK[(T) & 1];                                            \
    __builtin_amdgcn_s_setprio(1);                                                        \
    _Pragma("unroll") for (int nf = 0; nf < 4; nf++) {                                    \
      const char* kr = K_ + (nf * 16 + lrow) * 128;                                       \
      bf16x8 bk0 = *(const bf16x8*)(kr + ((16 * lk) ^ sw));                               \
      bf16x8 bk1 = *(const bf16x8*)(kr + ((64 + 16 * lk) ^ sw));                          \
      _Pragma("unroll") for (int qf = 0; qf < 2; qf++) {                                  \
        f32x4 z = {};                                                                     \
        z = __builtin_amdgcn_mfma_f32_16x16x32_bf16(bk0, aq[qf][0], z, 0, 0, 0);          \
        z = __builtin_amdgcn_mfma_f32_16x16x32_bf16(bk1, aq[qf][1], z, 0, 0, 0);          \
        SC[qf][nf] = z;                                                                   \
      }                                                                                   \
    }                                                                                     \
    __builtin_amdgcn_s_setprio(0);                                                        \
    if ((T) == tl) {                                                                      \
      int qo = (c & 1) * 32;                                                              \
      _Pragma("unroll") for (int qf = 0; qf < 2; qf++) {                                  \
        int qoff = qo + qf * 16 + lrow;                                                   \
        _Pragma("unroll") for (int nf = 0; nf < 4; nf++)                                  \
          _Pragma("unroll") for (int r = 0; r < 4; r++)                                   \
            if (nf * 16 + 4 * lk + r > qoff) SC[qf][nf][r] = -1e30f;                      \
      }                                                                                   \
    }                                                                                     \
  } while (0)

// softmax (tree-summed) + PV for the PREVIOUS tile TP held in SP
#define SMPV(TP, SP)                                                                      \
  do {                                                                                    \
    _Pragma("unroll") for (int qf = 0; qf < 2; qf++) {                                    \
      float s0 = 0.f, s1 = 0.f, s2 = 0.f, s3 = 0.f;                                       \
      _Pragma("unroll") for (int r = 0; r < 4; r++) {                                     \
        float p0 = ex2(SP[qf][0][r]); SP[qf][0][r] = p0; s0 += p0;                        \
        float p1 = ex2(SP[qf][1][r]); SP[qf][1][r] = p1; s1 += p1;                        \
        float p2 = ex2(SP[qf][2][r]); SP[qf][2][r] = p2; s2 += p2;                        \
        float p3 = ex2(SP[qf][3][r]); SP[qf][3][r] = p3; s3 += p3;                        \
      }                                                                                   \
      lp[qf] += (s0 + s1) + (s2 + s3);                                                    \
    }                                                                                     \
    const char* V_ = (const char*)lV[(TP) % 3];                                           \
    __builtin_amdgcn_s_setprio(1);                                                        \
    _Pragma("unroll") for (int np = 0; np < 2; np++) {                                    \
      bf16x8 pb[2];                                                                       \
      _Pragma("unroll") for (int qf = 0; qf < 2; qf++) {                                  \
        uint4 t4;                                                                         \
        t4.x = pkbf(SP[qf][np][0], SP[qf][np][1]);                                        \
        t4.y = pkbf(SP[qf][np][2], SP[qf][np][3]);                                        \
        t4.z = pkbf(SP[qf][np + 2][0], SP[qf][np + 2][1]);                                \
        t4.w = pkbf(SP[qf][np + 2][2], SP[qf][np + 2][3]);                                \
        pb[qf] = __builtin_bit_cast(bf16x8, t4);                                          \
      }                                                                                   \
      _Pragma("unroll") for (int dn = 0; dn < 4; dn++) {                                  \
        const char* vr = V_ + (dn * 16 + lrow) * 128;                                     \
        uint2 a0 = *(const uint2*)(vr + ((np * 32 + 8 * lk) ^ sw));                       \
        uint2 a1 = *(const uint2*)(vr + (((np + 2) * 32 + 8 * lk) ^ sw));                 \
        uint4 av;                                                                         \
        av.x = a0.x; av.y = a0.y; av.z = a1.x; av.w = a1.y;                               \
        bf16x8 va = __builtin_bit_cast(bf16x8, av);                                       \
        _Pragma("unroll") for (int qf = 0; qf < 2; qf++)                                  \
          o[qf][dn] = __builtin_amdgcn_mfma_f32_16x16x32_bf16(va, pb[qf], o[qf][dn],      \
                                                              0, 0, 0);                   \
      }                                                                                   \
    }                                                                                     \
    __builtin_amdgcn_s_setprio(0);                                                        \
  } while (0)

  STAGEK(0, 0); STAGEV(0, 0);
  // step 0: QK only (no prev yet)
  asm volatile("s_waitcnt vmcnt(2)" ::: "memory");   // K(0) landed; V(0) may fly
  __builtin_amdgcn_sched_barrier(0);
  __builtin_amdgcn_s_barrier();
  if (tl >= 1) { STAGEK(1, 1); STAGEV(1, 1); }
  QKS(0, sA);
  for (int t = 1; t <= tl; t += 2) {
    // ---- step t: cur = sB, prev = sA ----
    asm volatile("s_waitcnt vmcnt(2)" ::: "memory"); // drains K(t) and V(t-1)
    __builtin_amdgcn_sched_barrier(0);
    __builtin_amdgcn_s_barrier();
    if (t < tl) { STAGEK((t + 1) & 1, t + 1); STAGEV((t + 1) % 3, t + 1); }
    QKS(t, sB);
    SMPV(t - 1, sA);
    if (t + 1 <= tl) {
      // ---- step t+1: cur = sA, prev = sB ----
      asm volatile("s_waitcnt vmcnt(2)" ::: "memory");
      __builtin_amdgcn_sched_barrier(0);
      __builtin_amdgcn_s_barrier();
      if (t + 1 < tl) { STAGEK((t + 2) & 1, t + 2); STAGEV((t + 2) % 3, t + 2); }
      QKS(t + 1, sA);
      SMPV(t, sB);
    }
  }
  // drain tail: finish the last tile's softmax+PV (V(tl) fully landed + visible)
  asm volatile("s_waitcnt vmcnt(0)" ::: "memory");
  __builtin_amdgcn_sched_barrier(0);
  __builtin_amdgcn_s_barrier();
  if (tl & 1) { SMPV(tl, sB); } else { SMPV(tl, sA); }

  // epilogue: reduce lp across the 4 lk-lanes of each q-row, normalize, store b64 packs
#pragma unroll
  for (int qf = 0; qf < 2; qf++) {
    float s = lp[qf];
    s += __shfl_xor(s, 16);
    s += __shfl_xor(s, 32);
    float inv = 1.f / s;
    int qrow = c * 32 + qf * 16 + lrow;
    __bf16* op = O + (size_t)(b * 2048 + qrow) * 2048 + h * 64 + 4 * lk;
#pragma unroll
    for (int dn = 0; dn < 4; dn++) {
      bf16x4 stv;
#pragma unroll
      for (int r = 0; r < 4; r++) stv[r] = (__bf16)(o[qf][dn][r] * inv);
      *(bf16x4*)(op + dn * 16) = stv;
    }
  }
#undef STAGEK
#undef STAGEV
#undef QKS
#undef SMPV
}

extern "C" void kernel_launch(void* const* d_in, const int* in_sizes, int n_in,
                              void* d_out, int out_size, void* d_ws, size_t ws_size,
                              hipStream_t stream) {
  const float* x = (const float*)d_in[0];
  const float* wq = (const float*)d_in[1];
  const float* wk = (const float*)d_in[2];
  const float* wv = (const float*)d_in[3];
  const float* wo = (const float*)d_in[4];
  char* ws = (char*)d_ws;
  __bf16* xb    = (__bf16*)(ws + 0);          // 16,777,216
  __bf16* wqkvT = (__bf16*)(ws + 16777216);   // 12,582,912  [3072][2048]
  __bf16* woT   = (__bf16*)(ws + 29360128);   //  8,388,608
  __bf16* qb    = (__bf16*)(ws + 37748736);   // 16,777,216
  __bf16* kb    = (__bf16*)(ws + 54525952);   //  4,194,304
  __bf16* vt    = (__bf16*)(ws + 58720256);   //  4,194,304
  __bf16* ob    = (__bf16*)(ws + 62914560);   // 16,777,216
  float*  ct    = (float*)(ws + 79691776);    //    262,144
  float*  st    = (float*)(ws + 79953920);    //    262,144
  float* out = (float*)d_out;

  // one fused prep launch: cvt + wq/wk/wv/wo transpose-convert + rope table
  k_prep<<<14592, 256, 0, stream>>>(x, xb, wq, wk, wv, wo, wqkvT, woT, ct, st);
  // QKV: round-1 structure, grid 16x16 = 256 blocks -> every CU gets one block.
  k_gemm256<192, 12, 3, 0><<<256, 768, 0, stream>>>(xb, wqkvT, qb, kb, vt, ct, st, 2048, 16);
  // attn: descending-c dispatch, T15 P-pipeline.
  k_attn<<<1024, 256, 0, stream>>>(qb, kb, vt, ob);
  // WO: round-2 structure (3-deep A pipeline + XCD swizzle), measured faster for MODE 1.
  k_gemm3d<128, 8, 2, 1><<<256, 512, 0, stream>>>(ob, woT, out, 2048, 16);
}

// Round 11
// 160.858 us; speedup vs baseline: 1.0629x; 1.0629x over previous
//
#include <hip/hip_runtime.h>
#include <hip/hip_bf16.h>
#include <stdint.h>

typedef __attribute__((ext_vector_type(8))) __bf16 bf16x8;
typedef __attribute__((ext_vector_type(4))) __bf16 bf16x4;
typedef __attribute__((ext_vector_type(4))) float f32x4;

#define QSCALE (0.125f * 1.44269504f)

#define GL16(src, dst) __builtin_amdgcn_global_load_lds( \
    (const __attribute__((address_space(1))) void*)(src), \
    (__attribute__((address_space(3))) void*)(dst), 16, 0, 0)

static __device__ inline unsigned pkbf(float a, float b) {
  __bf16 x = (__bf16)a, y = (__bf16)b;
  unsigned short ux = __builtin_bit_cast(unsigned short, x);
  unsigned short uy = __builtin_bit_cast(unsigned short, y);
  return ((unsigned)uy << 16) | ux;
}

static __device__ inline float ex2(float x) {
#if __has_builtin(__builtin_amdgcn_exp2f)
  return __builtin_amdgcn_exp2f(x);
#else
  float r;
  asm("v_exp_f32 %0, %1" : "=v"(r) : "v"(x));
  return r;
#endif
}

// ---------------- fused prep: cvt + 4x transpose-convert + rope table ----------------
// One launch replaces six (r6 measured-best). Block ranges (all block-uniform):
//   [0,4096)      f32->bf16 cvt of x
//   [4096,8192)   wq  [2048][2048] -> bf16 [2048][2048]^T
//   [8192,9216)   wk  [2048][512]  -> bf16 [512][2048]^T   (into wqkvT+2048*2048)
//   [9216,10240)  wv  [2048][512]  -> bf16 [512][2048]^T   (into wqkvT+2560*2048)
//   [10240,14336) wo  [2048][2048] -> bf16 [2048][2048]^T
//   [14336,14592) rope cos/sin table [2048][32] f32
__global__ __launch_bounds__(256) void k_prep(const float* __restrict__ x,
                                              __bf16* __restrict__ xb,
                                              const float* __restrict__ wq,
                                              const float* __restrict__ wk,
                                              const float* __restrict__ wv,
                                              const float* __restrict__ wo,
                                              __bf16* __restrict__ wqkvT,
                                              __bf16* __restrict__ woT,
                                              float* __restrict__ ct,
                                              float* __restrict__ st) {
  int bid = blockIdx.x, tid = threadIdx.x;
  if (bid < 4096) {  // ---- cvt ----
    int i = bid * 256 + tid;
    const float4* p = (const float4*)(x) + (size_t)i * 2;
    float4 a = p[0], b = p[1];
    bf16x8 o;
    o[0] = (__bf16)a.x; o[1] = (__bf16)a.y; o[2] = (__bf16)a.z; o[3] = (__bf16)a.w;
    o[4] = (__bf16)b.x; o[5] = (__bf16)b.y; o[6] = (__bf16)b.z; o[7] = (__bf16)b.w;
    ((bf16x8*)xb)[i] = o;
    return;
  }
  if (bid >= 14336) {  // ---- rope table ----
    int i = (bid - 14336) * 256 + tid;
    int s = i >> 5, j = i & 31;
    float invf = powf(10000.0f, -(float)j / 32.0f);
    float fr = (float)s * invf;
    ct[i] = cosf(fr);
    st[i] = sinf(fr);
    return;
  }
  // ---- transpose-convert ----
  __shared__ float tile[32][33];
  const float* w;
  __bf16* wT;
  int N, r;
  if (bid < 8192)       { r = bid - 4096;  w = wq; wT = wqkvT;                        N = 2048; }
  else if (bid < 9216)  { r = bid - 8192;  w = wk; wT = wqkvT + (size_t)2048 * 2048;  N = 512; }
  else if (bid < 10240) { r = bid - 9216;  w = wv; wT = wqkvT + (size_t)2560 * 2048;  N = 512; }
  else                  { r = bid - 10240; w = wo; wT = woT;                          N = 2048; }
  int ntiles = N >> 5;
  int n0 = (r % ntiles) * 32, k0 = (r / ntiles) * 32;
  int tx = tid & 31, ty = tid >> 5;  // (32,8)
#pragma unroll
  for (int i = 0; i < 32; i += 8)
    tile[ty + i][tx] = w[(size_t)(k0 + ty + i) * N + n0 + tx];
  __syncthreads();
#pragma unroll
  for (int i = 0; i < 32; i += 8)
    wT[(size_t)(n0 + ty + i) * 2048 + k0 + tx] = (__bf16)tile[tx][ty + i];
}

// ---------------- QKV GEMM (round-1 measured-best): 2-deep, deferred af1 ----------------
// BM=256, NW waves, double-buffered LDS, staging 2 K-tiles ahead with counted vmcnt
// (never 0 mid-loop), raw s_barrier (no full drains), setprio on MFMA.
// MODE 0: BN=192, 12 waves (3Nx4M, 64-col head window/wave), grid 16x16=256 -> all CUs.
template <int BN, int NW, int WPN, int MODE>
__global__ __launch_bounds__(NW * 64, NW / 4) void k_gemm256(const __bf16* __restrict__ A,
                                                             const __bf16* __restrict__ BT,
                                                             void* __restrict__ C0,
                                                             __bf16* __restrict__ kb,
                                                             __bf16* __restrict__ vt,
                                                             const float* __restrict__ ct,
                                                             const float* __restrict__ st,
                                                             int K, int NBN) {
  constexpr int WPM = NW / WPN;         // waves along M
  constexpr int MF = 256 / WPM / 16;    // M-frags per wave
  constexpr int NF = BN / WPN / 16;     // N-frags per wave (64 cols)
  constexpr int MH = MF / 2;
  constexpr int CHA = 256 * 8;          // A 16B-chunks per K-tile
  constexpr int CHB = BN * 8;           // B 16B-chunks per K-tile
  constexpr int PA = CHA / (NW * 64);   // full A staging passes
  constexpr int RA = CHA - PA * NW * 64;// A remainder chunks (wave-aligned)
  constexpr int PB = CHB / (NW * 64);   // full B staging passes
  static_assert(CHB % (NW * 64) == 0, "B chunks must tile threads");
  static_assert(RA % 64 == 0, "A remainder must be wave-aligned");
  static_assert(NF == 4, "epilogue assumes 64-col wave window");
  __shared__ __align__(16) __bf16 lA[2][256 * 64];
  __shared__ __align__(16) __bf16 lB[2][BN * 64];
  int bm = (blockIdx.x / NBN) << 8;
  int bn = (blockIdx.x % NBN) * BN;
  int tid = threadIdx.x, l = tid & 63, w = tid >> 6;
  int wr = w / WPN, wc = w % WPN;
  int lrow = l & 15, lk = l >> 4;
  int NT = K >> 6;
  f32x4 acc[MF][NF] = {};

#define STG(T, BUF)                                                           \
  do {                                                                        \
    int k0_ = (T) << 6;                                                       \
    _Pragma("unroll") for (int i_ = 0; i_ < PA; i_++) {                       \
      int ch_ = i_ * (NW * 64) + tid;                                         \
      int r_ = ch_ >> 3, c_ = ch_ & 7;                                        \
      GL16(A + (size_t)(bm + r_) * K + k0_ + ((c_ ^ (r_ & 7)) << 3),          \
           &lA[BUF][(i_ * (NW * 64) + (w << 6)) * 8]);                        \
    }                                                                         \
    if constexpr (RA > 0) {                                                   \
      if (tid < RA) {                                                         \
        int ch_ = PA * (NW * 64) + tid;                                       \
        int r_ = ch_ >> 3, c_ = ch_ & 7;                                      \
        GL16(A + (size_t)(bm + r_) * K + k0_ + ((c_ ^ (r_ & 7)) << 3),        \
             &lA[BUF][(PA * (NW * 64) + (w << 6)) * 8]);                      \
      }                                                                       \
    }                                                                         \
    _Pragma("unroll") for (int i_ = 0; i_ < PB; i_++) {                       \
      int ch_ = i_ * (NW * 64) + tid;                                         \
      int r_ = ch_ >> 3, c_ = ch_ & 7;                                        \
      GL16(BT + (size_t)(bn + r_) * K + k0_ + ((c_ ^ (r_ & 7)) << 3),         \
           &lB[BUF][(i_ * (NW * 64) + (w << 6)) * 8]);                        \
    }                                                                         \
  } while (0)

#define WAITN()                                                               \
  do {                                                                        \
    if constexpr (RA > 0) {                                                   \
      if (w < (RA >> 6))                                                      \
        asm volatile("s_waitcnt vmcnt(%0)" ::"i"(PA + PB + 1) : "memory");    \
      else                                                                    \
        asm volatile("s_waitcnt vmcnt(%0)" ::"i"(PA + PB) : "memory");        \
    } else {                                                                  \
      asm volatile("s_waitcnt vmcnt(%0)" ::"i"(PA + PB) : "memory");          \
    }                                                                         \
  } while (0)

  STG(0, 0);
  STG(1, 1);
  WAITN();
  __builtin_amdgcn_sched_barrier(0);
  __builtin_amdgcn_s_barrier();

  for (int t = 0; t < NT; t++) {
    int buf = t & 1;
    const char* bA = (const char*)lA[buf];
    const char* bB = (const char*)lB[buf];
    bf16x8 bfr[NF][2], af0[MH][2], af1[MH][2];
#pragma unroll
    for (int nf = 0; nf < NF; nf++) {
      int row = wc * (NF * 16) + nf * 16 + lrow;
#pragma unroll
      for (int kc = 0; kc < 2; kc++)
        bfr[nf][kc] = *(const bf16x8*)(bB + row * 128 +
                                       ((kc * 64 + 16 * lk) ^ ((row & 7) << 4)));
    }
#pragma unroll
    for (int mf = 0; mf < MH; mf++) {
      int row = wr * (MF * 16) + mf * 16 + lrow;
#pragma unroll
      for (int kc = 0; kc < 2; kc++)
        af0[mf][kc] = *(const bf16x8*)(bA + row * 128 +
                                       ((kc * 64 + 16 * lk) ^ ((row & 7) << 4)));
    }
    __builtin_amdgcn_s_setprio(1);
#pragma unroll
    for (int kc = 0; kc < 2; kc++)
#pragma unroll
      for (int mf = 0; mf < MH; mf++)
#pragma unroll
        for (int nf = 0; nf < NF; nf++)
          acc[mf][nf] = __builtin_amdgcn_mfma_f32_16x16x32_bf16(af0[mf][kc], bfr[nf][kc],
                                                                acc[mf][nf], 0, 0, 0);
    __builtin_amdgcn_s_setprio(0);
#pragma unroll
    for (int mf = 0; mf < MH; mf++) {
      int row = wr * (MF * 16) + (MH + mf) * 16 + lrow;
#pragma unroll
      for (int kc = 0; kc < 2; kc++)
        af1[mf][kc] = *(const bf16x8*)(bA + row * 128 +
                                       ((kc * 64 + 16 * lk) ^ ((row & 7) << 4)));
    }
    asm volatile("s_waitcnt lgkmcnt(0)" ::: "memory");
    __builtin_amdgcn_sched_barrier(0);
    __builtin_amdgcn_s_barrier();        // all waves done reading buf
    if (t + 2 < NT) STG(t + 2, buf);     // overwrite freed buf, loads fly over MFMA
    __builtin_amdgcn_s_setprio(1);
#pragma unroll
    for (int kc = 0; kc < 2; kc++)
#pragma unroll
      for (int mf = 0; mf < MH; mf++)
#pragma unroll
        for (int nf = 0; nf < NF; nf++)
          acc[MH + mf][nf] = __builtin_amdgcn_mfma_f32_16x16x32_bf16(
              af1[mf][kc], bfr[nf][kc], acc[MH + mf][nf], 0, 0, 0);
    __builtin_amdgcn_s_setprio(0);
    if (t + 2 < NT) {
      WAITN();                           // t+1 ready, t+2 still flying
    } else {
      asm volatile("s_waitcnt vmcnt(0)" ::: "memory");
    }
    __builtin_amdgcn_sched_barrier(0);
    __builtin_amdgcn_s_barrier();
  }
#undef STG
#undef WAITN

  if constexpr (MODE == 0) {
    int wcb = bn + wc * 64;   // wave's 64-col window = one head
    __bf16* qb = (__bf16*)C0;
    if (wcb < 2048) {
#pragma unroll
      for (int mf = 0; mf < MF; mf++)
#pragma unroll
        for (int r = 0; r < 4; r++) {
          int row = bm + wr * (MF * 16) + mf * 16 + 4 * lk + r;
          int sidx = row & 2047;
#pragma unroll
          for (int nfl = 0; nfl < 2; nfl++) {
            int d = nfl * 16 + lrow;
            float c = ct[sidx * 32 + d], sn = st[sidx * 32 + d];
            float a = acc[mf][nfl][r], b2 = acc[mf][nfl + 2][r];
            qb[(size_t)row * 2048 + wcb + d] = (__bf16)((a * c - b2 * sn) * QSCALE);
            qb[(size_t)row * 2048 + wcb + d + 32] = (__bf16)((b2 * c + a * sn) * QSCALE);
          }
        }
    } else if (wcb < 2560) {
      int cb = wcb - 2048;
#pragma unroll
      for (int mf = 0; mf < MF; mf++)
#pragma unroll
        for (int r = 0; r < 4; r++) {
          int row = bm + wr * (MF * 16) + mf * 16 + 4 * lk + r;
          int sidx = row & 2047;
#pragma unroll
          for (int nfl = 0; nfl < 2; nfl++) {
            int d = nfl * 16 + lrow;
            float c = ct[sidx * 32 + d], sn = st[sidx * 32 + d];
            float a = acc[mf][nfl][r], b2 = acc[mf][nfl + 2][r];
            kb[(size_t)row * 512 + cb + d] = (__bf16)(a * c - b2 * sn);
            kb[(size_t)row * 512 + cb + d + 32] = (__bf16)(b2 * c + a * sn);
          }
        }
    } else {
      int hkk = (wcb - 2560) >> 6;
#pragma unroll
      for (int mf = 0; mf < MF; mf++)
#pragma unroll
        for (int nf = 0; nf < NF; nf++)
#pragma unroll
          for (int r = 0; r < 4; r++) {
            int row = bm + wr * (MF * 16) + mf * 16 + 4 * lk + r;
            int dd = nf * 16 + lrow;
            int bb = row >> 11, s = row & 2047;
            vt[(size_t)(((bb << 3) + hkk) * 64 + dd) * 2048 + s] = (__bf16)acc[mf][nf][r];
          }
    }
  } else {
    float* C = (float*)C0;
#pragma unroll
    for (int mf = 0; mf < MF; mf++)
#pragma unroll
      for (int nf = 0; nf < NF; nf++)
#pragma unroll
        for (int r = 0; r < 4; r++) {
          int row = bm + wr * (MF * 16) + mf * 16 + 4 * lk + r;
          int col = bn + wc * 64 + nf * 16 + lrow;
          C[(size_t)row * 2048 + col] = acc[mf][nf][r];
        }
  }
}

// ---------------- WO GEMM (round-2 measured-best): 3-deep A, upfront reads, swizzle ----
template <int BN, int NW, int WPN, int MODE>
__global__ __launch_bounds__(NW * 64, NW / 4) void k_gemm3d(const __bf16* __restrict__ A,
                                                            const __bf16* __restrict__ BT,
                                                            void* __restrict__ C0,
                                                            int K, int NBN) {
  constexpr int WPM = NW / WPN;
  constexpr int MF = 256 / WPM / 16;
  constexpr int NF = BN / WPN / 16;
  constexpr int MH = MF / 2;
  constexpr int CHA = 256 * 8;
  constexpr int CHB = BN * 8;
  constexpr int PA = CHA / (NW * 64);
  constexpr int RA = CHA - PA * NW * 64;
  constexpr int PB = CHB / (NW * 64);
  static_assert(CHB % (NW * 64) == 0, "B chunks must tile threads");
  static_assert(RA % 64 == 0, "A remainder must be wave-aligned");
  static_assert(NF == 4, "wave owns a 64-col window");
  constexpr int LB = PB;
  constexpr int LA0 = PA + (RA > 0 ? 1 : 0);
  constexpr int LA1 = PA;
  constexpr int NS0 = 2 * LA0 + LB, NS1 = 2 * LA1 + LB;
  constexpr int NM0 = LA0 + LB, NM1 = LA1 + LB;
  __shared__ __align__(16) __bf16 lA[3][256 * 64];
  __shared__ __align__(16) __bf16 lB[2][BN * 64];
  int bid = blockIdx.x;
  int lg = (bid & 7) * ((int)gridDim.x >> 3) + (bid >> 3);
  int bm = (lg / NBN) << 8;
  int bn = (lg % NBN) * BN;
  int tid = threadIdx.x, l = tid & 63, w = tid >> 6;
  int wr = w / WPN, wc = w % WPN;
  int lrow = l & 15, lk = l >> 4;
  int NT = K >> 6;
  f32x4 acc[MF][NF] = {};

#define STGA(T, BUF)                                                          \
  do {                                                                        \
    int k0_ = (T) << 6;                                                       \
    _Pragma("unroll") for (int i_ = 0; i_ < PA; i_++) {                       \
      int ch_ = i_ * (NW * 64) + tid;                                         \
      int r_ = ch_ >> 3, c_ = ch_ & 7;                                        \
      GL16(A + (size_t)(bm + r_) * K + k0_ + ((c_ ^ (r_ & 7)) << 3),          \
           &lA[BUF][(i_ * (NW * 64) + (w << 6)) * 8]);                        \
    }                                                                         \
    if constexpr (RA > 0) {                                                   \
      if (tid < RA) {                                                         \
        int ch_ = PA * (NW * 64) + tid;                                       \
        int r_ = ch_ >> 3, c_ = ch_ & 7;                                      \
        GL16(A + (size_t)(bm + r_) * K + k0_ + ((c_ ^ (r_ & 7)) << 3),        \
             &lA[BUF][(PA * (NW * 64) + (w << 6)) * 8]);                      \
      }                                                                       \
    }                                                                         \
  } while (0)

#define STGB(T, BUF)                                                          \
  do {                                                                        \
    int k0_ = (T) << 6;                                                       \
    _Pragma("unroll") for (int i_ = 0; i_ < PB; i_++) {                       \
      int ch_ = i_ * (NW * 64) + tid;                                         \
      int r_ = ch_ >> 3, c_ = ch_ & 7;                                        \
      GL16(BT + (size_t)(bn + r_) * K + k0_ + ((c_ ^ (r_ & 7)) << 3),         \
           &lB[BUF][(i_ * (NW * 64) + (w << 6)) * 8]);                        \
    }                                                                         \
  } while (0)

#define WAIT_STEADY()                                                         \
  do {                                                                        \
    if constexpr (RA > 0) {                                                   \
      if (w < (RA >> 6))                                                      \
        asm volatile("s_waitcnt vmcnt(%0)" ::"i"(NS0) : "memory");            \
      else                                                                    \
        asm volatile("s_waitcnt vmcnt(%0)" ::"i"(NS1) : "memory");            \
    } else {                                                                  \
      asm volatile("s_waitcnt vmcnt(%0)" ::"i"(NS1) : "memory");              \
    }                                                                         \
  } while (0)

#define WAIT_MID()                                                            \
  do {                                                                        \
    if constexpr (RA > 0) {                                                   \
      if (w < (RA >> 6))                                                      \
        asm volatile("s_waitcnt vmcnt(%0)" ::"i"(NM0) : "memory");            \
      else                                                                    \
        asm volatile("s_waitcnt vmcnt(%0)" ::"i"(NM1) : "memory");            \
    } else {                                                                  \
      asm volatile("s_waitcnt vmcnt(%0)" ::"i"(NM1) : "memory");              \
    }                                                                         \
  } while (0)

  STGB(0, 0); STGA(0, 0);
  STGB(1, 1); STGA(1, 1);
  STGA(2, 2);
  WAIT_STEADY();
  __builtin_amdgcn_sched_barrier(0);
  __builtin_amdgcn_s_barrier();

  int a0 = 0;
  for (int t = 0; t < NT; t++) {
    const char* bA = (const char*)lA[a0];
    const char* bB = (const char*)lB[t & 1];
    bf16x8 bfr[NF][2], af0[MH][2], af1[MH][2];
#pragma unroll
    for (int nf = 0; nf < NF; nf++) {
      int row = wc * (NF * 16) + nf * 16 + lrow;
#pragma unroll
      for (int kc = 0; kc < 2; kc++)
        bfr[nf][kc] = *(const bf16x8*)(bB + row * 128 +
                                       ((kc * 64 + 16 * lk) ^ ((row & 7) << 4)));
    }
#pragma unroll
    for (int mf = 0; mf < MH; mf++) {
      int row = wr * (MF * 16) + mf * 16 + lrow;
#pragma unroll
      for (int kc = 0; kc < 2; kc++)
        af0[mf][kc] = *(const bf16x8*)(bA + row * 128 +
                                       ((kc * 64 + 16 * lk) ^ ((row & 7) << 4)));
    }
#pragma unroll
    for (int mf = 0; mf < MH; mf++) {
      int row = wr * (MF * 16) + (MH + mf) * 16 + lrow;
#pragma unroll
      for (int kc = 0; kc < 2; kc++)
        af1[mf][kc] = *(const bf16x8*)(bA + row * 128 +
                                       ((kc * 64 + 16 * lk) ^ ((row & 7) << 4)));
    }
    __builtin_amdgcn_s_setprio(1);
#pragma unroll
    for (int kc = 0; kc < 2; kc++)
#pragma unroll
      for (int mf = 0; mf < MH; mf++)
#pragma unroll
        for (int nf = 0; nf < NF; nf++)
          acc[mf][nf] = __builtin_amdgcn_mfma_f32_16x16x32_bf16(af0[mf][kc], bfr[nf][kc],
                                                                acc[mf][nf], 0, 0, 0);
    __builtin_amdgcn_s_setprio(0);
    asm volatile("s_waitcnt lgkmcnt(0)" ::: "memory");
    __builtin_amdgcn_sched_barrier(0);
    __builtin_amdgcn_s_barrier();
    if (t + 2 < NT) STGB(t + 2, t & 1);
    if (t + 3 < NT) STGA(t + 3, a0);
    __builtin_amdgcn_s_setprio(1);
#pragma unroll
    for (int kc = 0; kc < 2; kc++)
#pragma unroll
      for (int mf = 0; mf < MH; mf++)
#pragma unroll
        for (int nf = 0; nf < NF; nf++)
          acc[MH + mf][nf] = __builtin_amdgcn_mfma_f32_16x16x32_bf16(
              af1[mf][kc], bfr[nf][kc], acc[MH + mf][nf], 0, 0, 0);
    __builtin_amdgcn_s_setprio(0);
    if (t + 3 < NT) {
      WAIT_STEADY();
    } else if (t + 2 < NT) {
      WAIT_MID();
    } else if (t + 1 < NT) {
      asm volatile("s_waitcnt vmcnt(0)" ::: "memory");
    }
    __builtin_amdgcn_sched_barrier(0);
    __builtin_amdgcn_s_barrier();
    a0 = (a0 == 2) ? 0 : a0 + 1;
  }
#undef STGA
#undef STGB
#undef WAIT_STEADY
#undef WAIT_MID

  float* C = (float*)C0;
#pragma unroll
  for (int mf = 0; mf < MF; mf++)
#pragma unroll
    for (int nf = 0; nf < NF; nf++)
#pragma unroll
      for (int r = 0; r < 4; r++) {
        int row = bm + wr * (MF * 16) + mf * 16 + 4 * lk + r;
        int col = bn + wc * 64 + nf * 16 + lrow;
        C[(size_t)row * 2048 + col] = acc[mf][nf][r];
      }
}

// ---------------- causal GQA flash attention v4c ----------------
// v4 structure (QBLK=32, grid 1024, descending-c dispatch — r5/r8 measured-best),
// launch_bounds(256,3), setprio on MFMA clusters. Ledger: TLP↑ spills (r4),
// 3-deep staging neutral (r9), T15 P-pipeline spills (r10) — this is the
// measured optimum of this block structure.
__global__ __launch_bounds__(256, 3) void k_attn(const __bf16* __restrict__ Q,
                                                 const __bf16* __restrict__ Kb,
                                                 const __bf16* __restrict__ VT,
                                                 __bf16* __restrict__ O) {
  __shared__ __align__(16) __bf16 lK[2][64 * 64];
  __shared__ __align__(16) __bf16 lV[2][64 * 64];
  int bid = blockIdx.x;            // 1024
  int c = 63 - (bid >> 4);         // q-chunk of 32 rows, most work first
  int hk = bid & 7;
  int b = (bid >> 3) & 1;
  int tid = threadIdx.x, l = tid & 63, w = tid >> 6;
  int h = hk * 4 + w;
  int lrow = l & 15, lk = l >> 4;
  int sw = (lrow & 7) << 4;
  int tl = c >> 1;                 // last kv tile index

#define STAGE(BUF, T)                                                                     \
  do {                                                                                    \
    int kv0_ = (T) * 64;                                                                  \
    _Pragma("unroll") for (int i_ = 0; i_ < 2; i_++) {                                    \
      int cb_ = i_ * 256 + w * 64;                                                        \
      int chunk_ = cb_ + l;                                                               \
      int row_ = chunk_ >> 3, cc_ = chunk_ & 7;                                           \
      GL16(Kb + (size_t)(b * 2048 + kv0_ + row_) * 512 + hk * 64 +                        \
               ((cc_ ^ (row_ & 7)) << 3),                                                 \
           &lK[BUF][cb_ * 8]);                                                            \
      GL16(VT + (size_t)((b * 8 + hk) * 64 + row_) * 2048 + kv0_ +                        \
               ((cc_ ^ (row_ & 7)) << 3),                                                 \
           &lV[BUF][cb_ * 8]);                                                            \
    }                                                                                     \
  } while (0)

  // Q fragments: 2 q-frags x 2 k-chunks, live in registers for the whole pass
  bf16x8 aq[2][2];
#pragma unroll
  for (int qf = 0; qf < 2; qf++) {
    int qrow = c * 32 + qf * 16 + lrow;
    const __bf16* qp = Q + (size_t)(b * 2048 + qrow) * 2048 + h * 64 + lk * 8;
    aq[qf][0] = *(const bf16x8*)qp;
    aq[qf][1] = *(const bf16x8*)(qp + 32);
  }
  f32x4 o[2][4] = {};
  float lp[2] = {0.f, 0.f};
  STAGE(0, 0);
  for (int t = 0, buf = 0; t <= tl; t++, buf ^= 1) {
    asm volatile("s_waitcnt vmcnt(0)" ::: "memory");
    __syncthreads();
    if (t < tl) STAGE(buf ^ 1, t + 1);
    const char* K_ = (const char*)lK[buf];
    const char* V_ = (const char*)lV[buf];
    // swapped QK^T: s4[qf][nf][r] = P^T[kv = nf*16+4*lk+r][q = lrow] (tile-local)
    f32x4 s4[2][4];
    __builtin_amdgcn_s_setprio(1);
#pragma unroll
    for (int nf = 0; nf < 4; nf++) {
      const char* kr = K_ + (nf * 16 + lrow) * 128;
      bf16x8 bk0 = *(const bf16x8*)(kr + ((16 * lk) ^ sw));
      bf16x8 bk1 = *(const bf16x8*)(kr + ((64 + 16 * lk) ^ sw));
#pragma unroll
      for (int qf = 0; qf < 2; qf++) {
        f32x4 z = {};
        z = __builtin_amdgcn_mfma_f32_16x16x32_bf16(bk0, aq[qf][0], z, 0, 0, 0);
        z = __builtin_amdgcn_mfma_f32_16x16x32_bf16(bk1, aq[qf][1], z, 0, 0, 0);
        s4[qf][nf] = z;
      }
    }
    __builtin_amdgcn_s_setprio(0);
    if (t == tl) {
      int qo = (c & 1) * 32;
#pragma unroll
      for (int qf = 0; qf < 2; qf++) {
        int qoff = qo + qf * 16 + lrow;
#pragma unroll
        for (int nf = 0; nf < 4; nf++)
#pragma unroll
          for (int r = 0; r < 4; r++)
            if (nf * 16 + 4 * lk + r > qoff) s4[qf][nf][r] = -1e30f;
      }
    }
    // no-max softmax: p = 2^s (s pre-scaled by log2e/8; bounded), in-lane partial sums
#pragma unroll
    for (int qf = 0; qf < 2; qf++) {
      float ps = 0.f;
#pragma unroll
      for (int nf = 0; nf < 4; nf++)
#pragma unroll
        for (int r = 0; r < 4; r++) {
          float pv = ex2(s4[qf][nf][r]);
          s4[qf][nf][r] = pv;
          ps += pv;
        }
      lp[qf] += ps;
    }
    // PV: o^T[d][q] += V^T * P^T, nf-tiles paired {np, np+2} into one 16x16x32 MFMA
    __builtin_amdgcn_s_setprio(1);
#pragma unroll
    for (int np = 0; np < 2; np++) {
      bf16x8 pb[2];
#pragma unroll
      for (int qf = 0; qf < 2; qf++) {
        uint4 t4;
        t4.x = pkbf(s4[qf][np][0], s4[qf][np][1]);
        t4.y = pkbf(s4[qf][np][2], s4[qf][np][3]);
        t4.z = pkbf(s4[qf][np + 2][0], s4[qf][np + 2][1]);
        t4.w = pkbf(s4[qf][np + 2][2], s4[qf][np + 2][3]);
        pb[qf] = __builtin_bit_cast(bf16x8, t4);
      }
#pragma unroll
      for (int dn = 0; dn < 4; dn++) {
        const char* vr = V_ + (dn * 16 + lrow) * 128;
        uint2 a0 = *(const uint2*)(vr + ((np * 32 + 8 * lk) ^ sw));
        uint2 a1 = *(const uint2*)(vr + (((np + 2) * 32 + 8 * lk) ^ sw));
        uint4 av;
        av.x = a0.x; av.y = a0.y; av.z = a1.x; av.w = a1.y;
        bf16x8 va = __builtin_bit_cast(bf16x8, av);
#pragma unroll
        for (int qf = 0; qf < 2; qf++)
          o[qf][dn] = __builtin_amdgcn_mfma_f32_16x16x32_bf16(va, pb[qf], o[qf][dn], 0, 0, 0);
      }
    }
    __builtin_amdgcn_s_setprio(0);
  }
  // epilogue: reduce lp across the 4 lk-lanes of each q-row, normalize, store b64 packs
#pragma unroll
  for (int qf = 0; qf < 2; qf++) {
    float s = lp[qf];
    s += __shfl_xor(s, 16);
    s += __shfl_xor(s, 32);
    float inv = 1.f / s;
    int qrow = c * 32 + qf * 16 + lrow;
    __bf16* op = O + (size_t)(b * 2048 + qrow) * 2048 + h * 64 + 4 * lk;
#pragma unroll
    for (int dn = 0; dn < 4; dn++) {
      bf16x4 stv;
#pragma unroll
      for (int r = 0; r < 4; r++) stv[r] = (__bf16)(o[qf][dn][r] * inv);
      *(bf16x4*)(op + dn * 16) = stv;
    }
  }
#undef STAGE
}

extern "C" void kernel_launch(void* const* d_in, const int* in_sizes, int n_in,
                              void* d_out, int out_size, void* d_ws, size_t ws_size,
                              hipStream_t stream) {
  const float* x = (const float*)d_in[0];
  const float* wq = (const float*)d_in[1];
  const float* wk = (const float*)d_in[2];
  const float* wv = (const float*)d_in[3];
  const float* wo = (const float*)d_in[4];
  char* ws = (char*)d_ws;
  __bf16* xb    = (__bf16*)(ws + 0);          // 16,777,216
  __bf16* wqkvT = (__bf16*)(ws + 16777216);   // 12,582,912  [3072][2048]
  __bf16* woT   = (__bf16*)(ws + 29360128);   //  8,388,608
  __bf16* qb    = (__bf16*)(ws + 37748736);   // 16,777,216
  __bf16* kb    = (__bf16*)(ws + 54525952);   //  4,194,304
  __bf16* vt    = (__bf16*)(ws + 58720256);   //  4,194,304
  __bf16* ob    = (__bf16*)(ws + 62914560);   // 16,777,216
  float*  ct    = (float*)(ws + 79691776);    //    262,144
  float*  st    = (float*)(ws + 79953920);    //    262,144
  float* out = (float*)d_out;

  // one fused prep launch: cvt + wq/wk/wv/wo transpose-convert + rope table
  k_prep<<<14592, 256, 0, stream>>>(x, xb, wq, wk, wv, wo, wqkvT, woT, ct, st);
  // QKV: round-1 structure, grid 16x16 = 256 blocks -> every CU gets one block.
  k_gemm256<192, 12, 3, 0><<<256, 768, 0, stream>>>(xb, wqkvT, qb, kb, vt, ct, st, 2048, 16);
  // attn: descending-c dispatch (r5/r8 measured-best).
  k_attn<<<1024, 256, 0, stream>>>(qb, kb, vt, ob);
  // WO: round-2 structure (3-deep A pipeline + XCD swizzle), measured faster for MODE 1.
  k_gemm3d<128, 8, 2, 1><<<256, 512, 0, stream>>>(ob, woT, out, 2048, 16);
}

// Round 12
// 157.757 us; speedup vs baseline: 1.0838x; 1.0197x over previous
//
#include <hip/hip_runtime.h>
#include <hip/hip_bf16.h>
#include <stdint.h>

typedef __attribute__((ext_vector_type(8))) __bf16 bf16x8;
typedef __attribute__((ext_vector_type(4))) __bf16 bf16x4;
typedef __attribute__((ext_vector_type(4))) float f32x4;

#define QSCALE (0.125f * 1.44269504f)

#define GL16(src, dst) __builtin_amdgcn_global_load_lds( \
    (const __attribute__((address_space(1))) void*)(src), \
    (__attribute__((address_space(3))) void*)(dst), 16, 0, 0)

static __device__ inline unsigned pkbf(float a, float b) {
  __bf16 x = (__bf16)a, y = (__bf16)b;
  unsigned short ux = __builtin_bit_cast(unsigned short, x);
  unsigned short uy = __builtin_bit_cast(unsigned short, y);
  return ((unsigned)uy << 16) | ux;
}

static __device__ inline float ex2(float x) {
#if __has_builtin(__builtin_amdgcn_exp2f)
  return __builtin_amdgcn_exp2f(x);
#else
  float r;
  asm("v_exp_f32 %0, %1" : "=v"(r) : "v"(x));
  return r;
#endif
}

// ---------------- fused prep: cvt + wq/wk/wv transpose-convert + rope table ----------
// (wo transpose is deferred into the attn launch's tail — it isn't needed until the
// WO GEMM, which runs after attn.) Block ranges (all block-uniform):
//   [0,4096)      f32->bf16 cvt of x
//   [4096,8192)   wq  [2048][2048] -> bf16 [2048][2048]^T
//   [8192,9216)   wk  [2048][512]  -> bf16 [512][2048]^T   (into wqkvT+2048*2048)
//   [9216,10240)  wv  [2048][512]  -> bf16 [512][2048]^T   (into wqkvT+2560*2048)
//   [10240,10496) rope cos/sin table [2048][32] f32
__global__ __launch_bounds__(256) void k_prep(const float* __restrict__ x,
                                              __bf16* __restrict__ xb,
                                              const float* __restrict__ wq,
                                              const float* __restrict__ wk,
                                              const float* __restrict__ wv,
                                              __bf16* __restrict__ wqkvT,
                                              float* __restrict__ ct,
                                              float* __restrict__ st) {
  int bid = blockIdx.x, tid = threadIdx.x;
  if (bid < 4096) {  // ---- cvt ----
    int i = bid * 256 + tid;
    const float4* p = (const float4*)(x) + (size_t)i * 2;
    float4 a = p[0], b = p[1];
    bf16x8 o;
    o[0] = (__bf16)a.x; o[1] = (__bf16)a.y; o[2] = (__bf16)a.z; o[3] = (__bf16)a.w;
    o[4] = (__bf16)b.x; o[5] = (__bf16)b.y; o[6] = (__bf16)b.z; o[7] = (__bf16)b.w;
    ((bf16x8*)xb)[i] = o;
    return;
  }
  if (bid >= 10240) {  // ---- rope table ----
    int i = (bid - 10240) * 256 + tid;
    int s = i >> 5, j = i & 31;
    float invf = powf(10000.0f, -(float)j / 32.0f);
    float fr = (float)s * invf;
    ct[i] = cosf(fr);
    st[i] = sinf(fr);
    return;
  }
  // ---- transpose-convert (wq/wk/wv) ----
  __shared__ float tile[32][33];
  const float* w;
  __bf16* wT;
  int N, r;
  if (bid < 8192)       { r = bid - 4096;  w = wq; wT = wqkvT;                        N = 2048; }
  else if (bid < 9216)  { r = bid - 8192;  w = wk; wT = wqkvT + (size_t)2048 * 2048;  N = 512; }
  else                  { r = bid - 9216;  w = wv; wT = wqkvT + (size_t)2560 * 2048;  N = 512; }
  int ntiles = N >> 5;
  int n0 = (r % ntiles) * 32, k0 = (r / ntiles) * 32;
  int tx = tid & 31, ty = tid >> 5;  // (32,8)
#pragma unroll
  for (int i = 0; i < 32; i += 8)
    tile[ty + i][tx] = w[(size_t)(k0 + ty + i) * N + n0 + tx];
  __syncthreads();
#pragma unroll
  for (int i = 0; i < 32; i += 8)
    wT[(size_t)(n0 + ty + i) * 2048 + k0 + tx] = (__bf16)tile[tx][ty + i];
}

// ---------------- QKV GEMM (round-1 measured-best): 2-deep, deferred af1 ----------------
// BM=256, NW waves, double-buffered LDS, staging 2 K-tiles ahead with counted vmcnt
// (never 0 mid-loop), raw s_barrier (no full drains), setprio on MFMA.
// MODE 0: BN=192, 12 waves (3Nx4M, 64-col head window/wave), grid 16x16=256 -> all CUs.
template <int BN, int NW, int WPN, int MODE>
__global__ __launch_bounds__(NW * 64, NW / 4) void k_gemm256(const __bf16* __restrict__ A,
                                                             const __bf16* __restrict__ BT,
                                                             void* __restrict__ C0,
                                                             __bf16* __restrict__ kb,
                                                             __bf16* __restrict__ vt,
                                                             const float* __restrict__ ct,
                                                             const float* __restrict__ st,
                                                             int K, int NBN) {
  constexpr int WPM = NW / WPN;         // waves along M
  constexpr int MF = 256 / WPM / 16;    // M-frags per wave
  constexpr int NF = BN / WPN / 16;     // N-frags per wave (64 cols)
  constexpr int MH = MF / 2;
  constexpr int CHA = 256 * 8;          // A 16B-chunks per K-tile
  constexpr int CHB = BN * 8;           // B 16B-chunks per K-tile
  constexpr int PA = CHA / (NW * 64);   // full A staging passes
  constexpr int RA = CHA - PA * NW * 64;// A remainder chunks (wave-aligned)
  constexpr int PB = CHB / (NW * 64);   // full B staging passes
  static_assert(CHB % (NW * 64) == 0, "B chunks must tile threads");
  static_assert(RA % 64 == 0, "A remainder must be wave-aligned");
  static_assert(NF == 4, "epilogue assumes 64-col wave window");
  __shared__ __align__(16) __bf16 lA[2][256 * 64];
  __shared__ __align__(16) __bf16 lB[2][BN * 64];
  int bm = (blockIdx.x / NBN) << 8;
  int bn = (blockIdx.x % NBN) * BN;
  int tid = threadIdx.x, l = tid & 63, w = tid >> 6;
  int wr = w / WPN, wc = w % WPN;
  int lrow = l & 15, lk = l >> 4;
  int NT = K >> 6;
  f32x4 acc[MF][NF] = {};

#define STG(T, BUF)                                                           \
  do {                                                                        \
    int k0_ = (T) << 6;                                                       \
    _Pragma("unroll") for (int i_ = 0; i_ < PA; i_++) {                       \
      int ch_ = i_ * (NW * 64) + tid;                                         \
      int r_ = ch_ >> 3, c_ = ch_ & 7;                                        \
      GL16(A + (size_t)(bm + r_) * K + k0_ + ((c_ ^ (r_ & 7)) << 3),          \
           &lA[BUF][(i_ * (NW * 64) + (w << 6)) * 8]);                        \
    }                                                                         \
    if constexpr (RA > 0) {                                                   \
      if (tid < RA) {                                                         \
        int ch_ = PA * (NW * 64) + tid;                                       \
        int r_ = ch_ >> 3, c_ = ch_ & 7;                                      \
        GL16(A + (size_t)(bm + r_) * K + k0_ + ((c_ ^ (r_ & 7)) << 3),        \
             &lA[BUF][(PA * (NW * 64) + (w << 6)) * 8]);                      \
      }                                                                       \
    }                                                                         \
    _Pragma("unroll") for (int i_ = 0; i_ < PB; i_++) {                       \
      int ch_ = i_ * (NW * 64) + tid;                                         \
      int r_ = ch_ >> 3, c_ = ch_ & 7;                                        \
      GL16(BT + (size_t)(bn + r_) * K + k0_ + ((c_ ^ (r_ & 7)) << 3),         \
           &lB[BUF][(i_ * (NW * 64) + (w << 6)) * 8]);                        \
    }                                                                         \
  } while (0)

#define WAITN()                                                               \
  do {                                                                        \
    if constexpr (RA > 0) {                                                   \
      if (w < (RA >> 6))                                                      \
        asm volatile("s_waitcnt vmcnt(%0)" ::"i"(PA + PB + 1) : "memory");    \
      else                                                                    \
        asm volatile("s_waitcnt vmcnt(%0)" ::"i"(PA + PB) : "memory");        \
    } else {                                                                  \
      asm volatile("s_waitcnt vmcnt(%0)" ::"i"(PA + PB) : "memory");          \
    }                                                                         \
  } while (0)

  STG(0, 0);
  STG(1, 1);
  WAITN();
  __builtin_amdgcn_sched_barrier(0);
  __builtin_amdgcn_s_barrier();

  for (int t = 0; t < NT; t++) {
    int buf = t & 1;
    const char* bA = (const char*)lA[buf];
    const char* bB = (const char*)lB[buf];
    bf16x8 bfr[NF][2], af0[MH][2], af1[MH][2];
#pragma unroll
    for (int nf = 0; nf < NF; nf++) {
      int row = wc * (NF * 16) + nf * 16 + lrow;
#pragma unroll
      for (int kc = 0; kc < 2; kc++)
        bfr[nf][kc] = *(const bf16x8*)(bB + row * 128 +
                                       ((kc * 64 + 16 * lk) ^ ((row & 7) << 4)));
    }
#pragma unroll
    for (int mf = 0; mf < MH; mf++) {
      int row = wr * (MF * 16) + mf * 16 + lrow;
#pragma unroll
      for (int kc = 0; kc < 2; kc++)
        af0[mf][kc] = *(const bf16x8*)(bA + row * 128 +
                                       ((kc * 64 + 16 * lk) ^ ((row & 7) << 4)));
    }
    __builtin_amdgcn_s_setprio(1);
#pragma unroll
    for (int kc = 0; kc < 2; kc++)
#pragma unroll
      for (int mf = 0; mf < MH; mf++)
#pragma unroll
        for (int nf = 0; nf < NF; nf++)
          acc[mf][nf] = __builtin_amdgcn_mfma_f32_16x16x32_bf16(af0[mf][kc], bfr[nf][kc],
                                                                acc[mf][nf], 0, 0, 0);
    __builtin_amdgcn_s_setprio(0);
#pragma unroll
    for (int mf = 0; mf < MH; mf++) {
      int row = wr * (MF * 16) + (MH + mf) * 16 + lrow;
#pragma unroll
      for (int kc = 0; kc < 2; kc++)
        af1[mf][kc] = *(const bf16x8*)(bA + row * 128 +
                                       ((kc * 64 + 16 * lk) ^ ((row & 7) << 4)));
    }
    asm volatile("s_waitcnt lgkmcnt(0)" ::: "memory");
    __builtin_amdgcn_sched_barrier(0);
    __builtin_amdgcn_s_barrier();        // all waves done reading buf
    if (t + 2 < NT) STG(t + 2, buf);     // overwrite freed buf, loads fly over MFMA
    __builtin_amdgcn_s_setprio(1);
#pragma unroll
    for (int kc = 0; kc < 2; kc++)
#pragma unroll
      for (int mf = 0; mf < MH; mf++)
#pragma unroll
        for (int nf = 0; nf < NF; nf++)
          acc[MH + mf][nf] = __builtin_amdgcn_mfma_f32_16x16x32_bf16(
              af1[mf][kc], bfr[nf][kc], acc[MH + mf][nf], 0, 0, 0);
    __builtin_amdgcn_s_setprio(0);
    if (t + 2 < NT) {
      WAITN();                           // t+1 ready, t+2 still flying
    } else {
      asm volatile("s_waitcnt vmcnt(0)" ::: "memory");
    }
    __builtin_amdgcn_sched_barrier(0);
    __builtin_amdgcn_s_barrier();
  }
#undef STG
#undef WAITN

  if constexpr (MODE == 0) {
    int wcb = bn + wc * 64;   // wave's 64-col window = one head
    __bf16* qb = (__bf16*)C0;
    if (wcb < 2048) {
#pragma unroll
      for (int mf = 0; mf < MF; mf++)
#pragma unroll
        for (int r = 0; r < 4; r++) {
          int row = bm + wr * (MF * 16) + mf * 16 + 4 * lk + r;
          int sidx = row & 2047;
#pragma unroll
          for (int nfl = 0; nfl < 2; nfl++) {
            int d = nfl * 16 + lrow;
            float c = ct[sidx * 32 + d], sn = st[sidx * 32 + d];
            float a = acc[mf][nfl][r], b2 = acc[mf][nfl + 2][r];
            qb[(size_t)row * 2048 + wcb + d] = (__bf16)((a * c - b2 * sn) * QSCALE);
            qb[(size_t)row * 2048 + wcb + d + 32] = (__bf16)((b2 * c + a * sn) * QSCALE);
          }
        }
    } else if (wcb < 2560) {
      int cb = wcb - 2048;
#pragma unroll
      for (int mf = 0; mf < MF; mf++)
#pragma unroll
        for (int r = 0; r < 4; r++) {
          int row = bm + wr * (MF * 16) + mf * 16 + 4 * lk + r;
          int sidx = row & 2047;
#pragma unroll
          for (int nfl = 0; nfl < 2; nfl++) {
            int d = nfl * 16 + lrow;
            float c = ct[sidx * 32 + d], sn = st[sidx * 32 + d];
            float a = acc[mf][nfl][r], b2 = acc[mf][nfl + 2][r];
            kb[(size_t)row * 512 + cb + d] = (__bf16)(a * c - b2 * sn);
            kb[(size_t)row * 512 + cb + d + 32] = (__bf16)(b2 * c + a * sn);
          }
        }
    } else {
      int hkk = (wcb - 2560) >> 6;
#pragma unroll
      for (int mf = 0; mf < MF; mf++)
#pragma unroll
        for (int nf = 0; nf < NF; nf++)
#pragma unroll
          for (int r = 0; r < 4; r++) {
            int row = bm + wr * (MF * 16) + mf * 16 + 4 * lk + r;
            int dd = nf * 16 + lrow;
            int bb = row >> 11, s = row & 2047;
            vt[(size_t)(((bb << 3) + hkk) * 64 + dd) * 2048 + s] = (__bf16)acc[mf][nf][r];
          }
    }
  } else {
    float* C = (float*)C0;
#pragma unroll
    for (int mf = 0; mf < MF; mf++)
#pragma unroll
      for (int nf = 0; nf < NF; nf++)
#pragma unroll
        for (int r = 0; r < 4; r++) {
          int row = bm + wr * (MF * 16) + mf * 16 + 4 * lk + r;
          int col = bn + wc * 64 + nf * 16 + lrow;
          C[(size_t)row * 2048 + col] = acc[mf][nf][r];
        }
  }
}

// ---------------- WO GEMM (round-2 measured-best): 3-deep A, upfront reads, swizzle ----
template <int BN, int NW, int WPN, int MODE>
__global__ __launch_bounds__(NW * 64, NW / 4) void k_gemm3d(const __bf16* __restrict__ A,
                                                            const __bf16* __restrict__ BT,
                                                            void* __restrict__ C0,
                                                            int K, int NBN) {
  constexpr int WPM = NW / WPN;
  constexpr int MF = 256 / WPM / 16;
  constexpr int NF = BN / WPN / 16;
  constexpr int MH = MF / 2;
  constexpr int CHA = 256 * 8;
  constexpr int CHB = BN * 8;
  constexpr int PA = CHA / (NW * 64);
  constexpr int RA = CHA - PA * NW * 64;
  constexpr int PB = CHB / (NW * 64);
  static_assert(CHB % (NW * 64) == 0, "B chunks must tile threads");
  static_assert(RA % 64 == 0, "A remainder must be wave-aligned");
  static_assert(NF == 4, "wave owns a 64-col window");
  constexpr int LB = PB;
  constexpr int LA0 = PA + (RA > 0 ? 1 : 0);
  constexpr int LA1 = PA;
  constexpr int NS0 = 2 * LA0 + LB, NS1 = 2 * LA1 + LB;
  constexpr int NM0 = LA0 + LB, NM1 = LA1 + LB;
  __shared__ __align__(16) __bf16 lA[3][256 * 64];
  __shared__ __align__(16) __bf16 lB[2][BN * 64];
  int bid = blockIdx.x;
  int lg = (bid & 7) * ((int)gridDim.x >> 3) + (bid >> 3);
  int bm = (lg / NBN) << 8;
  int bn = (lg % NBN) * BN;
  int tid = threadIdx.x, l = tid & 63, w = tid >> 6;
  int wr = w / WPN, wc = w % WPN;
  int lrow = l & 15, lk = l >> 4;
  int NT = K >> 6;
  f32x4 acc[MF][NF] = {};

#define STGA(T, BUF)                                                          \
  do {                                                                        \
    int k0_ = (T) << 6;                                                       \
    _Pragma("unroll") for (int i_ = 0; i_ < PA; i_++) {                       \
      int ch_ = i_ * (NW * 64) + tid;                                         \
      int r_ = ch_ >> 3, c_ = ch_ & 7;                                        \
      GL16(A + (size_t)(bm + r_) * K + k0_ + ((c_ ^ (r_ & 7)) << 3),          \
           &lA[BUF][(i_ * (NW * 64) + (w << 6)) * 8]);                        \
    }                                                                         \
    if constexpr (RA > 0) {                                                   \
      if (tid < RA) {                                                         \
        int ch_ = PA * (NW * 64) + tid;                                       \
        int r_ = ch_ >> 3, c_ = ch_ & 7;                                      \
        GL16(A + (size_t)(bm + r_) * K + k0_ + ((c_ ^ (r_ & 7)) << 3),        \
             &lA[BUF][(PA * (NW * 64) + (w << 6)) * 8]);                      \
      }                                                                       \
    }                                                                         \
  } while (0)

#define STGB(T, BUF)                                                          \
  do {                                                                        \
    int k0_ = (T) << 6;                                                       \
    _Pragma("unroll") for (int i_ = 0; i_ < PB; i_++) {                       \
      int ch_ = i_ * (NW * 64) + tid;                                         \
      int r_ = ch_ >> 3, c_ = ch_ & 7;                                        \
      GL16(BT + (size_t)(bn + r_) * K + k0_ + ((c_ ^ (r_ & 7)) << 3),         \
           &lB[BUF][(i_ * (NW * 64) + (w << 6)) * 8]);                        \
    }                                                                         \
  } while (0)

#define WAIT_STEADY()                                                         \
  do {                                                                        \
    if constexpr (RA > 0) {                                                   \
      if (w < (RA >> 6))                                                      \
        asm volatile("s_waitcnt vmcnt(%0)" ::"i"(NS0) : "memory");            \
      else                                                                    \
        asm volatile("s_waitcnt vmcnt(%0)" ::"i"(NS1) : "memory");            \
    } else {                                                                  \
      asm volatile("s_waitcnt vmcnt(%0)" ::"i"(NS1) : "memory");              \
    }                                                                         \
  } while (0)

#define WAIT_MID()                                                            \
  do {                                                                        \
    if constexpr (RA > 0) {                                                   \
      if (w < (RA >> 6))                                                      \
        asm volatile("s_waitcnt vmcnt(%0)" ::"i"(NM0) : "memory");            \
      else                                                                    \
        asm volatile("s_waitcnt vmcnt(%0)" ::"i"(NM1) : "memory");            \
    } else {                                                                  \
      asm volatile("s_waitcnt vmcnt(%0)" ::"i"(NM1) : "memory");              \
    }                                                                         \
  } while (0)

  STGB(0, 0); STGA(0, 0);
  STGB(1, 1); STGA(1, 1);
  STGA(2, 2);
  WAIT_STEADY();
  __builtin_amdgcn_sched_barrier(0);
  __builtin_amdgcn_s_barrier();

  int a0 = 0;
  for (int t = 0; t < NT; t++) {
    const char* bA = (const char*)lA[a0];
    const char* bB = (const char*)lB[t & 1];
    bf16x8 bfr[NF][2], af0[MH][2], af1[MH][2];
#pragma unroll
    for (int nf = 0; nf < NF; nf++) {
      int row = wc * (NF * 16) + nf * 16 + lrow;
#pragma unroll
      for (int kc = 0; kc < 2; kc++)
        bfr[nf][kc] = *(const bf16x8*)(bB + row * 128 +
                                       ((kc * 64 + 16 * lk) ^ ((row & 7) << 4)));
    }
#pragma unroll
    for (int mf = 0; mf < MH; mf++) {
      int row = wr * (MF * 16) + mf * 16 + lrow;
#pragma unroll
      for (int kc = 0; kc < 2; kc++)
        af0[mf][kc] = *(const bf16x8*)(bA + row * 128 +
                                       ((kc * 64 + 16 * lk) ^ ((row & 7) << 4)));
    }
#pragma unroll
    for (int mf = 0; mf < MH; mf++) {
      int row = wr * (MF * 16) + (MH + mf) * 16 + lrow;
#pragma unroll
      for (int kc = 0; kc < 2; kc++)
        af1[mf][kc] = *(const bf16x8*)(bA + row * 128 +
                                       ((kc * 64 + 16 * lk) ^ ((row & 7) << 4)));
    }
    __builtin_amdgcn_s_setprio(1);
#pragma unroll
    for (int kc = 0; kc < 2; kc++)
#pragma unroll
      for (int mf = 0; mf < MH; mf++)
#pragma unroll
        for (int nf = 0; nf < NF; nf++)
          acc[mf][nf] = __builtin_amdgcn_mfma_f32_16x16x32_bf16(af0[mf][kc], bfr[nf][kc],
                                                                acc[mf][nf], 0, 0, 0);
    __builtin_amdgcn_s_setprio(0);
    asm volatile("s_waitcnt lgkmcnt(0)" ::: "memory");
    __builtin_amdgcn_sched_barrier(0);
    __builtin_amdgcn_s_barrier();
    if (t + 2 < NT) STGB(t + 2, t & 1);
    if (t + 3 < NT) STGA(t + 3, a0);
    __builtin_amdgcn_s_setprio(1);
#pragma unroll
    for (int kc = 0; kc < 2; kc++)
#pragma unroll
      for (int mf = 0; mf < MH; mf++)
#pragma unroll
        for (int nf = 0; nf < NF; nf++)
          acc[MH + mf][nf] = __builtin_amdgcn_mfma_f32_16x16x32_bf16(
              af1[mf][kc], bfr[nf][kc], acc[MH + mf][nf], 0, 0, 0);
    __builtin_amdgcn_s_setprio(0);
    if (t + 3 < NT) {
      WAIT_STEADY();
    } else if (t + 2 < NT) {
      WAIT_MID();
    } else if (t + 1 < NT) {
      asm volatile("s_waitcnt vmcnt(0)" ::: "memory");
    }
    __builtin_amdgcn_sched_barrier(0);
    __builtin_amdgcn_s_barrier();
    a0 = (a0 == 2) ? 0 : a0 + 1;
  }
#undef STGA
#undef STGB
#undef WAIT_STEADY
#undef WAIT_MID

  float* C = (float*)C0;
#pragma unroll
  for (int mf = 0; mf < MF; mf++)
#pragma unroll
    for (int nf = 0; nf < NF; nf++)
#pragma unroll
      for (int r = 0; r < 4; r++) {
        int row = bm + wr * (MF * 16) + mf * 16 + 4 * lk + r;
        int col = bn + wc * 64 + nf * 16 + lrow;
        C[(size_t)row * 2048 + col] = acc[mf][nf][r];
      }
}

// ---------------- causal GQA flash attention v4c + wo-transpose tail-fill ----------
// Blocks [0,1024): v4 attn (QBLK=32, descending-c, setprio, (256,3) — r8/r11
// measured-best, unchanged). Blocks [1024,5120): the deferred wo transpose-convert
// (4096 32x32 tiles) — dispatched after the attn blocks, these fill CUs freed by
// early-retiring light attn blocks (time-weighted occupancy was ~24%), hiding
// ~8 us of streaming traffic under the attn tail. woT is complete at kernel end,
// before the WO GEMM launch. LDS overlaid: the f32 tile reuses lK's space.
__global__ __launch_bounds__(256, 3) void k_attn(const __bf16* __restrict__ Q,
                                                 const __bf16* __restrict__ Kb,
                                                 const __bf16* __restrict__ VT,
                                                 __bf16* __restrict__ O,
                                                 const float* __restrict__ wo,
                                                 __bf16* __restrict__ woT) {
  __shared__ __align__(16) __bf16 lK[2][64 * 64];
  __shared__ __align__(16) __bf16 lV[2][64 * 64];
  int bid = blockIdx.x;            // 5120
  int tid = threadIdx.x;
  if (bid >= 1024) {  // ---- deferred wo [2048][2048] -> bf16 [2048][2048]^T ----
    float* tile = (float*)lK;      // 32x33 f32 = 4224 B, overlaid on lK (16 KB)
    int r = bid - 1024;
    int n0 = (r & 63) * 32, k0 = (r >> 6) * 32;
    int tx = tid & 31, ty = tid >> 5;  // (32,8)
#pragma unroll
    for (int i = 0; i < 32; i += 8)
      tile[(ty + i) * 33 + tx] = wo[(size_t)(k0 + ty + i) * 2048 + n0 + tx];
    __syncthreads();
#pragma unroll
    for (int i = 0; i < 32; i += 8)
      woT[(size_t)(n0 + ty + i) * 2048 + k0 + tx] = (__bf16)tile[tx * 33 + ty + i];
    return;
  }
  int c = 63 - (bid >> 4);         // q-chunk of 32 rows, most work first
  int hk = bid & 7;
  int b = (bid >> 3) & 1;
  int l = tid & 63, w = tid >> 6;
  int h = hk * 4 + w;
  int lrow = l & 15, lk = l >> 4;
  int sw = (lrow & 7) << 4;
  int tl = c >> 1;                 // last kv tile index

#define STAGE(BUF, T)                                                                     \
  do {                                                                                    \
    int kv0_ = (T) * 64;                                                                  \
    _Pragma("unroll") for (int i_ = 0; i_ < 2; i_++) {                                    \
      int cb_ = i_ * 256 + w * 64;                                                        \
      int chunk_ = cb_ + l;                                                               \
      int row_ = chunk_ >> 3, cc_ = chunk_ & 7;                                           \
      GL16(Kb + (size_t)(b * 2048 + kv0_ + row_) * 512 + hk * 64 +                        \
               ((cc_ ^ (row_ & 7)) << 3),                                                 \
           &lK[BUF][cb_ * 8]);                                                            \
      GL16(VT + (size_t)((b * 8 + hk) * 64 + row_) * 2048 + kv0_ +                        \
               ((cc_ ^ (row_ & 7)) << 3),                                                 \
           &lV[BUF][cb_ * 8]);                                                            \
    }                                                                                     \
  } while (0)

  // Q fragments: 2 q-frags x 2 k-chunks, live in registers for the whole pass
  bf16x8 aq[2][2];
#pragma unroll
  for (int qf = 0; qf < 2; qf++) {
    int qrow = c * 32 + qf * 16 + lrow;
    const __bf16* qp = Q + (size_t)(b * 2048 + qrow) * 2048 + h * 64 + lk * 8;
    aq[qf][0] = *(const bf16x8*)qp;
    aq[qf][1] = *(const bf16x8*)(qp + 32);
  }
  f32x4 o[2][4] = {};
  float lp[2] = {0.f, 0.f};
  STAGE(0, 0);
  for (int t = 0, buf = 0; t <= tl; t++, buf ^= 1) {
    asm volatile("s_waitcnt vmcnt(0)" ::: "memory");
    __syncthreads();
    if (t < tl) STAGE(buf ^ 1, t + 1);
    const char* K_ = (const char*)lK[buf];
    const char* V_ = (const char*)lV[buf];
    // swapped QK^T: s4[qf][nf][r] = P^T[kv = nf*16+4*lk+r][q = lrow] (tile-local)
    f32x4 s4[2][4];
    __builtin_amdgcn_s_setprio(1);
#pragma unroll
    for (int nf = 0; nf < 4; nf++) {
      const char* kr = K_ + (nf * 16 + lrow) * 128;
      bf16x8 bk0 = *(const bf16x8*)(kr + ((16 * lk) ^ sw));
      bf16x8 bk1 = *(const bf16x8*)(kr + ((64 + 16 * lk) ^ sw));
#pragma unroll
      for (int qf = 0; qf < 2; qf++) {
        f32x4 z = {};
        z = __builtin_amdgcn_mfma_f32_16x16x32_bf16(bk0, aq[qf][0], z, 0, 0, 0);
        z = __builtin_amdgcn_mfma_f32_16x16x32_bf16(bk1, aq[qf][1], z, 0, 0, 0);
        s4[qf][nf] = z;
      }
    }
    __builtin_amdgcn_s_setprio(0);
    if (t == tl) {
      int qo = (c & 1) * 32;
#pragma unroll
      for (int qf = 0; qf < 2; qf++) {
        int qoff = qo + qf * 16 + lrow;
#pragma unroll
        for (int nf = 0; nf < 4; nf++)
#pragma unroll
          for (int r = 0; r < 4; r++)
            if (nf * 16 + 4 * lk + r > qoff) s4[qf][nf][r] = -1e30f;
      }
    }
    // no-max softmax: p = 2^s (s pre-scaled by log2e/8; bounded), in-lane partial sums
#pragma unroll
    for (int qf = 0; qf < 2; qf++) {
      float ps = 0.f;
#pragma unroll
      for (int nf = 0; nf < 4; nf++)
#pragma unroll
        for (int r = 0; r < 4; r++) {
          float pv = ex2(s4[qf][nf][r]);
          s4[qf][nf][r] = pv;
          ps += pv;
        }
      lp[qf] += ps;
    }
    // PV: o^T[d][q] += V^T * P^T, nf-tiles paired {np, np+2} into one 16x16x32 MFMA
    __builtin_amdgcn_s_setprio(1);
#pragma unroll
    for (int np = 0; np < 2; np++) {
      bf16x8 pb[2];
#pragma unroll
      for (int qf = 0; qf < 2; qf++) {
        uint4 t4;
        t4.x = pkbf(s4[qf][np][0], s4[qf][np][1]);
        t4.y = pkbf(s4[qf][np][2], s4[qf][np][3]);
        t4.z = pkbf(s4[qf][np + 2][0], s4[qf][np + 2][1]);
        t4.w = pkbf(s4[qf][np + 2][2], s4[qf][np + 2][3]);
        pb[qf] = __builtin_bit_cast(bf16x8, t4);
      }
#pragma unroll
      for (int dn = 0; dn < 4; dn++) {
        const char* vr = V_ + (dn * 16 + lrow) * 128;
        uint2 a0 = *(const uint2*)(vr + ((np * 32 + 8 * lk) ^ sw));
        uint2 a1 = *(const uint2*)(vr + (((np + 2) * 32 + 8 * lk) ^ sw));
        uint4 av;
        av.x = a0.x; av.y = a0.y; av.z = a1.x; av.w = a1.y;
        bf16x8 va = __builtin_bit_cast(bf16x8, av);
#pragma unroll
        for (int qf = 0; qf < 2; qf++)
          o[qf][dn] = __builtin_amdgcn_mfma_f32_16x16x32_bf16(va, pb[qf], o[qf][dn], 0, 0, 0);
      }
    }
    __builtin_amdgcn_s_setprio(0);
  }
  // epilogue: reduce lp across the 4 lk-lanes of each q-row, normalize, store b64 packs
#pragma unroll
  for (int qf = 0; qf < 2; qf++) {
    float s = lp[qf];
    s += __shfl_xor(s, 16);
    s += __shfl_xor(s, 32);
    float inv = 1.f / s;
    int qrow = c * 32 + qf * 16 + lrow;
    __bf16* op = O + (size_t)(b * 2048 + qrow) * 2048 + h * 64 + 4 * lk;
#pragma unroll
    for (int dn = 0; dn < 4; dn++) {
      bf16x4 stv;
#pragma unroll
      for (int r = 0; r < 4; r++) stv[r] = (__bf16)(o[qf][dn][r] * inv);
      *(bf16x4*)(op + dn * 16) = stv;
    }
  }
#undef STAGE
}

extern "C" void kernel_launch(void* const* d_in, const int* in_sizes, int n_in,
                              void* d_out, int out_size, void* d_ws, size_t ws_size,
                              hipStream_t stream) {
  const float* x = (const float*)d_in[0];
  const float* wq = (const float*)d_in[1];
  const float* wk = (const float*)d_in[2];
  const float* wv = (const float*)d_in[3];
  const float* wo = (const float*)d_in[4];
  char* ws = (char*)d_ws;
  __bf16* xb    = (__bf16*)(ws + 0);          // 16,777,216
  __bf16* wqkvT = (__bf16*)(ws + 16777216);   // 12,582,912  [3072][2048]
  __bf16* woT   = (__bf16*)(ws + 29360128);   //  8,388,608
  __bf16* qb    = (__bf16*)(ws + 37748736);   // 16,777,216
  __bf16* kb    = (__bf16*)(ws + 54525952);   //  4,194,304
  __bf16* vt    = (__bf16*)(ws + 58720256);   //  4,194,304
  __bf16* ob    = (__bf16*)(ws + 62914560);   // 16,777,216
  float*  ct    = (float*)(ws + 79691776);    //    262,144
  float*  st    = (float*)(ws + 79953920);    //    262,144
  float* out = (float*)d_out;

  // prep: cvt + wq/wk/wv transpose-convert + rope table (wo transpose deferred)
  k_prep<<<10496, 256, 0, stream>>>(x, xb, wq, wk, wv, wqkvT, ct, st);
  // QKV: round-1 structure, grid 16x16 = 256 blocks -> every CU gets one block.
  k_gemm256<192, 12, 3, 0><<<256, 768, 0, stream>>>(xb, wqkvT, qb, kb, vt, ct, st, 2048, 16);
  // attn (blocks 0..1023, descending-c) + deferred wo transpose tail-fill (1024..5119).
  k_attn<<<5120, 256, 0, stream>>>(qb, kb, vt, ob, wo, woT);
  // WO: round-2 structure (3-deep A pipeline + XCD swizzle), measured faster for MODE 1.
  k_gemm3d<128, 8, 2, 1><<<256, 512, 0, stream>>>(ob, woT, out, 2048, 16);
}

// Round 13
// 157.558 us; speedup vs baseline: 1.0852x; 1.0013x over previous
//
#include <hip/hip_runtime.h>
#include <hip/hip_bf16.h>
#include <stdint.h>

typedef __attribute__((ext_vector_type(8))) __bf16 bf16x8;
typedef __attribute__((ext_vector_type(4))) __bf16 bf16x4;
typedef __attribute__((ext_vector_type(4))) float f32x4;

#define QSCALE (0.125f * 1.44269504f)

#define GL16(src, dst) __builtin_amdgcn_global_load_lds( \
    (const __attribute__((address_space(1))) void*)(src), \
    (__attribute__((address_space(3))) void*)(dst), 16, 0, 0)

static __device__ inline unsigned pkbf(float a, float b) {
  __bf16 x = (__bf16)a, y = (__bf16)b;
  unsigned short ux = __builtin_bit_cast(unsigned short, x);
  unsigned short uy = __builtin_bit_cast(unsigned short, y);
  return ((unsigned)uy << 16) | ux;
}

static __device__ inline float ex2(float x) {
#if __has_builtin(__builtin_amdgcn_exp2f)
  return __builtin_amdgcn_exp2f(x);
#else
  float r;
  asm("v_exp_f32 %0, %1" : "=v"(r) : "v"(x));
  return r;
#endif
}

// ---------------- fused prep: cvt + wq/wk/wv transpose-convert + rope table ----------
// (wo transpose is deferred into the attn launch's tail — it isn't needed until the
// WO GEMM, which runs after attn.) Block ranges (all block-uniform):
//   [0,4096)      f32->bf16 cvt of x
//   [4096,8192)   wq  [2048][2048] -> bf16 [2048][2048]^T
//   [8192,9216)   wk  [2048][512]  -> bf16 [512][2048]^T   (into wqkvT+2048*2048)
//   [9216,10240)  wv  [2048][512]  -> bf16 [512][2048]^T   (into wqkvT+2560*2048)
//   [10240,10496) rope cos/sin table [2048][32] f32
__global__ __launch_bounds__(256) void k_prep(const float* __restrict__ x,
                                              __bf16* __restrict__ xb,
                                              const float* __restrict__ wq,
                                              const float* __restrict__ wk,
                                              const float* __restrict__ wv,
                                              __bf16* __restrict__ wqkvT,
                                              float* __restrict__ ct,
                                              float* __restrict__ st) {
  int bid = blockIdx.x, tid = threadIdx.x;
  if (bid < 4096) {  // ---- cvt ----
    int i = bid * 256 + tid;
    const float4* p = (const float4*)(x) + (size_t)i * 2;
    float4 a = p[0], b = p[1];
    bf16x8 o;
    o[0] = (__bf16)a.x; o[1] = (__bf16)a.y; o[2] = (__bf16)a.z; o[3] = (__bf16)a.w;
    o[4] = (__bf16)b.x; o[5] = (__bf16)b.y; o[6] = (__bf16)b.z; o[7] = (__bf16)b.w;
    ((bf16x8*)xb)[i] = o;
    return;
  }
  if (bid >= 10240) {  // ---- rope table ----
    int i = (bid - 10240) * 256 + tid;
    int s = i >> 5, j = i & 31;
    float invf = powf(10000.0f, -(float)j / 32.0f);
    float fr = (float)s * invf;
    ct[i] = cosf(fr);
    st[i] = sinf(fr);
    return;
  }
  // ---- transpose-convert (wq/wk/wv) ----
  __shared__ float tile[32][33];
  const float* w;
  __bf16* wT;
  int N, r;
  if (bid < 8192)       { r = bid - 4096;  w = wq; wT = wqkvT;                        N = 2048; }
  else if (bid < 9216)  { r = bid - 8192;  w = wk; wT = wqkvT + (size_t)2048 * 2048;  N = 512; }
  else                  { r = bid - 9216;  w = wv; wT = wqkvT + (size_t)2560 * 2048;  N = 512; }
  int ntiles = N >> 5;
  int n0 = (r % ntiles) * 32, k0 = (r / ntiles) * 32;
  int tx = tid & 31, ty = tid >> 5;  // (32,8)
#pragma unroll
  for (int i = 0; i < 32; i += 8)
    tile[ty + i][tx] = w[(size_t)(k0 + ty + i) * N + n0 + tx];
  __syncthreads();
#pragma unroll
  for (int i = 0; i < 32; i += 8)
    wT[(size_t)(n0 + ty + i) * 2048 + k0 + tx] = (__bf16)tile[tx][ty + i];
}

// ---------------- QKV GEMM (round-1 measured-best): 2-deep, deferred af1 ----------------
// BM=256, NW waves, double-buffered LDS, staging 2 K-tiles ahead with counted vmcnt
// (never 0 mid-loop), raw s_barrier (no full drains), setprio on MFMA.
// MODE 0: BN=192, 12 waves (3Nx4M, 64-col head window/wave), grid 16x16=256 -> all CUs.
template <int BN, int NW, int WPN, int MODE>
__global__ __launch_bounds__(NW * 64, NW / 4) void k_gemm256(const __bf16* __restrict__ A,
                                                             const __bf16* __restrict__ BT,
                                                             void* __restrict__ C0,
                                                             __bf16* __restrict__ kb,
                                                             __bf16* __restrict__ vt,
                                                             const float* __restrict__ ct,
                                                             const float* __restrict__ st,
                                                             int K, int NBN) {
  constexpr int WPM = NW / WPN;         // waves along M
  constexpr int MF = 256 / WPM / 16;    // M-frags per wave
  constexpr int NF = BN / WPN / 16;     // N-frags per wave (64 cols)
  constexpr int MH = MF / 2;
  constexpr int CHA = 256 * 8;          // A 16B-chunks per K-tile
  constexpr int CHB = BN * 8;           // B 16B-chunks per K-tile
  constexpr int PA = CHA / (NW * 64);   // full A staging passes
  constexpr int RA = CHA - PA * NW * 64;// A remainder chunks (wave-aligned)
  constexpr int PB = CHB / (NW * 64);   // full B staging passes
  static_assert(CHB % (NW * 64) == 0, "B chunks must tile threads");
  static_assert(RA % 64 == 0, "A remainder must be wave-aligned");
  static_assert(NF == 4, "epilogue assumes 64-col wave window");
  __shared__ __align__(16) __bf16 lA[2][256 * 64];
  __shared__ __align__(16) __bf16 lB[2][BN * 64];
  int bm = (blockIdx.x / NBN) << 8;
  int bn = (blockIdx.x % NBN) * BN;
  int tid = threadIdx.x, l = tid & 63, w = tid >> 6;
  int wr = w / WPN, wc = w % WPN;
  int lrow = l & 15, lk = l >> 4;
  int NT = K >> 6;
  f32x4 acc[MF][NF] = {};

#define STG(T, BUF)                                                           \
  do {                                                                        \
    int k0_ = (T) << 6;                                                       \
    _Pragma("unroll") for (int i_ = 0; i_ < PA; i_++) {                       \
      int ch_ = i_ * (NW * 64) + tid;                                         \
      int r_ = ch_ >> 3, c_ = ch_ & 7;                                        \
      GL16(A + (size_t)(bm + r_) * K + k0_ + ((c_ ^ (r_ & 7)) << 3),          \
           &lA[BUF][(i_ * (NW * 64) + (w << 6)) * 8]);                        \
    }                                                                         \
    if constexpr (RA > 0) {                                                   \
      if (tid < RA) {                                                         \
        int ch_ = PA * (NW * 64) + tid;                                       \
        int r_ = ch_ >> 3, c_ = ch_ & 7;                                      \
        GL16(A + (size_t)(bm + r_) * K + k0_ + ((c_ ^ (r_ & 7)) << 3),        \
             &lA[BUF][(PA * (NW * 64) + (w << 6)) * 8]);                      \
      }                                                                       \
    }                                                                         \
    _Pragma("unroll") for (int i_ = 0; i_ < PB; i_++) {                       \
      int ch_ = i_ * (NW * 64) + tid;                                         \
      int r_ = ch_ >> 3, c_ = ch_ & 7;                                        \
      GL16(BT + (size_t)(bn + r_) * K + k0_ + ((c_ ^ (r_ & 7)) << 3),         \
           &lB[BUF][(i_ * (NW * 64) + (w << 6)) * 8]);                        \
    }                                                                         \
  } while (0)

#define WAITN()                                                               \
  do {                                                                        \
    if constexpr (RA > 0) {                                                   \
      if (w < (RA >> 6))                                                      \
        asm volatile("s_waitcnt vmcnt(%0)" ::"i"(PA + PB + 1) : "memory");    \
      else                                                                    \
        asm volatile("s_waitcnt vmcnt(%0)" ::"i"(PA + PB) : "memory");        \
    } else {                                                                  \
      asm volatile("s_waitcnt vmcnt(%0)" ::"i"(PA + PB) : "memory");          \
    }                                                                         \
  } while (0)

  STG(0, 0);
  STG(1, 1);
  WAITN();
  __builtin_amdgcn_sched_barrier(0);
  __builtin_amdgcn_s_barrier();

  for (int t = 0; t < NT; t++) {
    int buf = t & 1;
    const char* bA = (const char*)lA[buf];
    const char* bB = (const char*)lB[buf];
    bf16x8 bfr[NF][2], af0[MH][2], af1[MH][2];
#pragma unroll
    for (int nf = 0; nf < NF; nf++) {
      int row = wc * (NF * 16) + nf * 16 + lrow;
#pragma unroll
      for (int kc = 0; kc < 2; kc++)
        bfr[nf][kc] = *(const bf16x8*)(bB + row * 128 +
                                       ((kc * 64 + 16 * lk) ^ ((row & 7) << 4)));
    }
#pragma unroll
    for (int mf = 0; mf < MH; mf++) {
      int row = wr * (MF * 16) + mf * 16 + lrow;
#pragma unroll
      for (int kc = 0; kc < 2; kc++)
        af0[mf][kc] = *(const bf16x8*)(bA + row * 128 +
                                       ((kc * 64 + 16 * lk) ^ ((row & 7) << 4)));
    }
    __builtin_amdgcn_s_setprio(1);
#pragma unroll
    for (int kc = 0; kc < 2; kc++)
#pragma unroll
      for (int mf = 0; mf < MH; mf++)
#pragma unroll
        for (int nf = 0; nf < NF; nf++)
          acc[mf][nf] = __builtin_amdgcn_mfma_f32_16x16x32_bf16(af0[mf][kc], bfr[nf][kc],
                                                                acc[mf][nf], 0, 0, 0);
    __builtin_amdgcn_s_setprio(0);
#pragma unroll
    for (int mf = 0; mf < MH; mf++) {
      int row = wr * (MF * 16) + (MH + mf) * 16 + lrow;
#pragma unroll
      for (int kc = 0; kc < 2; kc++)
        af1[mf][kc] = *(const bf16x8*)(bA + row * 128 +
                                       ((kc * 64 + 16 * lk) ^ ((row & 7) << 4)));
    }
    asm volatile("s_waitcnt lgkmcnt(0)" ::: "memory");
    __builtin_amdgcn_sched_barrier(0);
    __builtin_amdgcn_s_barrier();        // all waves done reading buf
    if (t + 2 < NT) STG(t + 2, buf);     // overwrite freed buf, loads fly over MFMA
    __builtin_amdgcn_s_setprio(1);
#pragma unroll
    for (int kc = 0; kc < 2; kc++)
#pragma unroll
      for (int mf = 0; mf < MH; mf++)
#pragma unroll
        for (int nf = 0; nf < NF; nf++)
          acc[MH + mf][nf] = __builtin_amdgcn_mfma_f32_16x16x32_bf16(
              af1[mf][kc], bfr[nf][kc], acc[MH + mf][nf], 0, 0, 0);
    __builtin_amdgcn_s_setprio(0);
    if (t + 2 < NT) {
      WAITN();                           // t+1 ready, t+2 still flying
    } else {
      asm volatile("s_waitcnt vmcnt(0)" ::: "memory");
    }
    __builtin_amdgcn_sched_barrier(0);
    __builtin_amdgcn_s_barrier();
  }
#undef STG
#undef WAITN

  if constexpr (MODE == 0) {
    int wcb = bn + wc * 64;   // wave's 64-col window = one head
    __bf16* qb = (__bf16*)C0;
    if (wcb < 2048) {
#pragma unroll
      for (int mf = 0; mf < MF; mf++)
#pragma unroll
        for (int r = 0; r < 4; r++) {
          int row = bm + wr * (MF * 16) + mf * 16 + 4 * lk + r;
          int sidx = row & 2047;
#pragma unroll
          for (int nfl = 0; nfl < 2; nfl++) {
            int d = nfl * 16 + lrow;
            float c = ct[sidx * 32 + d], sn = st[sidx * 32 + d];
            float a = acc[mf][nfl][r], b2 = acc[mf][nfl + 2][r];
            qb[(size_t)row * 2048 + wcb + d] = (__bf16)((a * c - b2 * sn) * QSCALE);
            qb[(size_t)row * 2048 + wcb + d + 32] = (__bf16)((b2 * c + a * sn) * QSCALE);
          }
        }
    } else if (wcb < 2560) {
      int cb = wcb - 2048;
#pragma unroll
      for (int mf = 0; mf < MF; mf++)
#pragma unroll
        for (int r = 0; r < 4; r++) {
          int row = bm + wr * (MF * 16) + mf * 16 + 4 * lk + r;
          int sidx = row & 2047;
#pragma unroll
          for (int nfl = 0; nfl < 2; nfl++) {
            int d = nfl * 16 + lrow;
            float c = ct[sidx * 32 + d], sn = st[sidx * 32 + d];
            float a = acc[mf][nfl][r], b2 = acc[mf][nfl + 2][r];
            kb[(size_t)row * 512 + cb + d] = (__bf16)(a * c - b2 * sn);
            kb[(size_t)row * 512 + cb + d + 32] = (__bf16)(b2 * c + a * sn);
          }
        }
    } else {
      int hkk = (wcb - 2560) >> 6;
#pragma unroll
      for (int mf = 0; mf < MF; mf++)
#pragma unroll
        for (int nf = 0; nf < NF; nf++)
#pragma unroll
          for (int r = 0; r < 4; r++) {
            int row = bm + wr * (MF * 16) + mf * 16 + 4 * lk + r;
            int dd = nf * 16 + lrow;
            int bb = row >> 11, s = row & 2047;
            vt[(size_t)(((bb << 3) + hkk) * 64 + dd) * 2048 + s] = (__bf16)acc[mf][nf][r];
          }
    }
  } else {
    float* C = (float*)C0;
#pragma unroll
    for (int mf = 0; mf < MF; mf++)
#pragma unroll
      for (int nf = 0; nf < NF; nf++)
#pragma unroll
        for (int r = 0; r < 4; r++) {
          int row = bm + wr * (MF * 16) + mf * 16 + 4 * lk + r;
          int col = bn + wc * 64 + nf * 16 + lrow;
          C[(size_t)row * 2048 + col] = acc[mf][nf][r];
        }
  }
}

// ---------------- WO GEMM (round-2 measured-best): 3-deep A, upfront reads, swizzle ----
template <int BN, int NW, int WPN, int MODE>
__global__ __launch_bounds__(NW * 64, NW / 4) void k_gemm3d(const __bf16* __restrict__ A,
                                                            const __bf16* __restrict__ BT,
                                                            void* __restrict__ C0,
                                                            int K, int NBN) {
  constexpr int WPM = NW / WPN;
  constexpr int MF = 256 / WPM / 16;
  constexpr int NF = BN / WPN / 16;
  constexpr int MH = MF / 2;
  constexpr int CHA = 256 * 8;
  constexpr int CHB = BN * 8;
  constexpr int PA = CHA / (NW * 64);
  constexpr int RA = CHA - PA * NW * 64;
  constexpr int PB = CHB / (NW * 64);
  static_assert(CHB % (NW * 64) == 0, "B chunks must tile threads");
  static_assert(RA % 64 == 0, "A remainder must be wave-aligned");
  static_assert(NF == 4, "wave owns a 64-col window");
  constexpr int LB = PB;
  constexpr int LA0 = PA + (RA > 0 ? 1 : 0);
  constexpr int LA1 = PA;
  constexpr int NS0 = 2 * LA0 + LB, NS1 = 2 * LA1 + LB;
  constexpr int NM0 = LA0 + LB, NM1 = LA1 + LB;
  __shared__ __align__(16) __bf16 lA[3][256 * 64];
  __shared__ __align__(16) __bf16 lB[2][BN * 64];
  int bid = blockIdx.x;
  int lg = (bid & 7) * ((int)gridDim.x >> 3) + (bid >> 3);
  int bm = (lg / NBN) << 8;
  int bn = (lg % NBN) * BN;
  int tid = threadIdx.x, l = tid & 63, w = tid >> 6;
  int wr = w / WPN, wc = w % WPN;
  int lrow = l & 15, lk = l >> 4;
  int NT = K >> 6;
  f32x4 acc[MF][NF] = {};

#define STGA(T, BUF)                                                          \
  do {                                                                        \
    int k0_ = (T) << 6;                                                       \
    _Pragma("unroll") for (int i_ = 0; i_ < PA; i_++) {                       \
      int ch_ = i_ * (NW * 64) + tid;                                         \
      int r_ = ch_ >> 3, c_ = ch_ & 7;                                        \
      GL16(A + (size_t)(bm + r_) * K + k0_ + ((c_ ^ (r_ & 7)) << 3),          \
           &lA[BUF][(i_ * (NW * 64) + (w << 6)) * 8]);                        \
    }                                                                         \
    if constexpr (RA > 0) {                                                   \
      if (tid < RA) {                                                         \
        int ch_ = PA * (NW * 64) + tid;                                       \
        int r_ = ch_ >> 3, c_ = ch_ & 7;                                      \
        GL16(A + (size_t)(bm + r_) * K + k0_ + ((c_ ^ (r_ & 7)) << 3),        \
             &lA[BUF][(PA * (NW * 64) + (w << 6)) * 8]);                      \
      }                                                                       \
    }                                                                         \
  } while (0)

#define STGB(T, BUF)                                                          \
  do {                                                                        \
    int k0_ = (T) << 6;                                                       \
    _Pragma("unroll") for (int i_ = 0; i_ < PB; i_++) {                       \
      int ch_ = i_ * (NW * 64) + tid;                                         \
      int r_ = ch_ >> 3, c_ = ch_ & 7;                                        \
      GL16(BT + (size_t)(bn + r_) * K + k0_ + ((c_ ^ (r_ & 7)) << 3),         \
           &lB[BUF][(i_ * (NW * 64) + (w << 6)) * 8]);                        \
    }                                                                         \
  } while (0)

#define WAIT_STEADY()                                                         \
  do {                                                                        \
    if constexpr (RA > 0) {                                                   \
      if (w < (RA >> 6))                                                      \
        asm volatile("s_waitcnt vmcnt(%0)" ::"i"(NS0) : "memory");            \
      else                                                                    \
        asm volatile("s_waitcnt vmcnt(%0)" ::"i"(NS1) : "memory");            \
    } else {                                                                  \
      asm volatile("s_waitcnt vmcnt(%0)" ::"i"(NS1) : "memory");              \
    }                                                                         \
  } while (0)

#define WAIT_MID()                                                            \
  do {                                                                        \
    if constexpr (RA > 0) {                                                   \
      if (w < (RA >> 6))                                                      \
        asm volatile("s_waitcnt vmcnt(%0)" ::"i"(NM0) : "memory");            \
      else                                                                    \
        asm volatile("s_waitcnt vmcnt(%0)" ::"i"(NM1) : "memory");            \
    } else {                                                                  \
      asm volatile("s_waitcnt vmcnt(%0)" ::"i"(NM1) : "memory");              \
    }                                                                         \
  } while (0)

  STGB(0, 0); STGA(0, 0);
  STGB(1, 1); STGA(1, 1);
  STGA(2, 2);
  WAIT_STEADY();
  __builtin_amdgcn_sched_barrier(0);
  __builtin_amdgcn_s_barrier();

  int a0 = 0;
  for (int t = 0; t < NT; t++) {
    const char* bA = (const char*)lA[a0];
    const char* bB = (const char*)lB[t & 1];
    bf16x8 bfr[NF][2], af0[MH][2], af1[MH][2];
#pragma unroll
    for (int nf = 0; nf < NF; nf++) {
      int row = wc * (NF * 16) + nf * 16 + lrow;
#pragma unroll
      for (int kc = 0; kc < 2; kc++)
        bfr[nf][kc] = *(const bf16x8*)(bB + row * 128 +
                                       ((kc * 64 + 16 * lk) ^ ((row & 7) << 4)));
    }
#pragma unroll
    for (int mf = 0; mf < MH; mf++) {
      int row = wr * (MF * 16) + mf * 16 + lrow;
#pragma unroll
      for (int kc = 0; kc < 2; kc++)
        af0[mf][kc] = *(const bf16x8*)(bA + row * 128 +
                                       ((kc * 64 + 16 * lk) ^ ((row & 7) << 4)));
    }
#pragma unroll
    for (int mf = 0; mf < MH; mf++) {
      int row = wr * (MF * 16) + (MH + mf) * 16 + lrow;
#pragma unroll
      for (int kc = 0; kc < 2; kc++)
        af1[mf][kc] = *(const bf16x8*)(bA + row * 128 +
                                       ((kc * 64 + 16 * lk) ^ ((row & 7) << 4)));
    }
    __builtin_amdgcn_s_setprio(1);
#pragma unroll
    for (int kc = 0; kc < 2; kc++)
#pragma unroll
      for (int mf = 0; mf < MH; mf++)
#pragma unroll
        for (int nf = 0; nf < NF; nf++)
          acc[mf][nf] = __builtin_amdgcn_mfma_f32_16x16x32_bf16(af0[mf][kc], bfr[nf][kc],
                                                                acc[mf][nf], 0, 0, 0);
    __builtin_amdgcn_s_setprio(0);
    asm volatile("s_waitcnt lgkmcnt(0)" ::: "memory");
    __builtin_amdgcn_sched_barrier(0);
    __builtin_amdgcn_s_barrier();
    if (t + 2 < NT) STGB(t + 2, t & 1);
    if (t + 3 < NT) STGA(t + 3, a0);
    __builtin_amdgcn_s_setprio(1);
#pragma unroll
    for (int kc = 0; kc < 2; kc++)
#pragma unroll
      for (int mf = 0; mf < MH; mf++)
#pragma unroll
        for (int nf = 0; nf < NF; nf++)
          acc[MH + mf][nf] = __builtin_amdgcn_mfma_f32_16x16x32_bf16(
              af1[mf][kc], bfr[nf][kc], acc[MH + mf][nf], 0, 0, 0);
    __builtin_amdgcn_s_setprio(0);
    if (t + 3 < NT) {
      WAIT_STEADY();
    } else if (t + 2 < NT) {
      WAIT_MID();
    } else if (t + 1 < NT) {
      asm volatile("s_waitcnt vmcnt(0)" ::: "memory");
    }
    __builtin_amdgcn_sched_barrier(0);
    __builtin_amdgcn_s_barrier();
    a0 = (a0 == 2) ? 0 : a0 + 1;
  }
#undef STGA
#undef STGB
#undef WAIT_STEADY
#undef WAIT_MID

  float* C = (float*)C0;
#pragma unroll
  for (int mf = 0; mf < MF; mf++)
#pragma unroll
    for (int nf = 0; nf < NF; nf++)
#pragma unroll
      for (int r = 0; r < 4; r++) {
        int row = bm + wr * (MF * 16) + mf * 16 + 4 * lk + r;
        int col = bn + wc * 64 + nf * 16 + lrow;
        C[(size_t)row * 2048 + col] = acc[mf][nf][r];
      }
}

// ---------------- causal GQA flash attention v4c + wo-transpose tail-fill ----------
// Blocks [0,1024): v4 attn (QBLK=32, descending-c, setprio, (256,3) — r8/r11
// measured-best, unchanged). Blocks [1024,5120): the deferred wo transpose-convert
// (4096 32x32 tiles) — dispatched after the attn blocks, these fill CUs freed by
// early-retiring light attn blocks, hiding most of ~8 us of streaming traffic under
// the attn tail. woT is complete at kernel end, before the WO GEMM launch.
__global__ __launch_bounds__(256, 3) void k_attn(const __bf16* __restrict__ Q,
                                                 const __bf16* __restrict__ Kb,
                                                 const __bf16* __restrict__ VT,
                                                 __bf16* __restrict__ O,
                                                 const float* __restrict__ wo,
                                                 __bf16* __restrict__ woT) {
  __shared__ __align__(16) __bf16 lK[2][64 * 64];
  __shared__ __align__(16) __bf16 lV[2][64 * 64];
  int bid = blockIdx.x;            // 5120
  int tid = threadIdx.x;
  if (bid >= 1024) {  // ---- deferred wo [2048][2048] -> bf16 [2048][2048]^T ----
    float* tile = (float*)lK;      // 32x33 f32 = 4224 B, overlaid on lK (16 KB)
    int r = bid - 1024;
    int n0 = (r & 63) * 32, k0 = (r >> 6) * 32;
    int tx = tid & 31, ty = tid >> 5;  // (32,8)
#pragma unroll
    for (int i = 0; i < 32; i += 8)
      tile[(ty + i) * 33 + tx] = wo[(size_t)(k0 + ty + i) * 2048 + n0 + tx];
    __syncthreads();
#pragma unroll
    for (int i = 0; i < 32; i += 8)
      woT[(size_t)(n0 + ty + i) * 2048 + k0 + tx] = (__bf16)tile[tx * 33 + ty + i];
    return;
  }
  int c = 63 - (bid >> 4);         // q-chunk of 32 rows, most work first
  int hk = bid & 7;
  int b = (bid >> 3) & 1;
  int l = tid & 63, w = tid >> 6;
  int h = hk * 4 + w;
  int lrow = l & 15, lk = l >> 4;
  int sw = (lrow & 7) << 4;
  int tl = c >> 1;                 // last kv tile index

#define STAGE(BUF, T)                                                                     \
  do {                                                                                    \
    int kv0_ = (T) * 64;                                                                  \
    _Pragma("unroll") for (int i_ = 0; i_ < 2; i_++) {                                    \
      int cb_ = i_ * 256 + w * 64;                                                        \
      int chunk_ = cb_ + l;                                                               \
      int row_ = chunk_ >> 3, cc_ = chunk_ & 7;                                           \
      GL16(Kb + (size_t)(b * 2048 + kv0_ + row_) * 512 + hk * 64 +                        \
               ((cc_ ^ (row_ & 7)) << 3),                                                 \
           &lK[BUF][cb_ * 8]);                                                            \
      GL16(VT + (size_t)((b * 8 + hk) * 64 + row_) * 2048 + kv0_ +                        \
               ((cc_ ^ (row_ & 7)) << 3),                                                 \
           &lV[BUF][cb_ * 8]);                                                            \
    }                                                                                     \
  } while (0)

  // Q fragments: 2 q-frags x 2 k-chunks, live in registers for the whole pass
  bf16x8 aq[2][2];
#pragma unroll
  for (int qf = 0; qf < 2; qf++) {
    int qrow = c * 32 + qf * 16 + lrow;
    const __bf16* qp = Q + (size_t)(b * 2048 + qrow) * 2048 + h * 64 + lk * 8;
    aq[qf][0] = *(const bf16x8*)qp;
    aq[qf][1] = *(const bf16x8*)(qp + 32);
  }
  f32x4 o[2][4] = {};
  float lp[2] = {0.f, 0.f};
  STAGE(0, 0);
  for (int t = 0, buf = 0; t <= tl; t++, buf ^= 1) {
    asm volatile("s_waitcnt vmcnt(0)" ::: "memory");
    __syncthreads();
    if (t < tl) STAGE(buf ^ 1, t + 1);
    const char* K_ = (const char*)lK[buf];
    const char* V_ = (const char*)lV[buf];
    // swapped QK^T: s4[qf][nf][r] = P^T[kv = nf*16+4*lk+r][q = lrow] (tile-local)
    f32x4 s4[2][4];
    __builtin_amdgcn_s_setprio(1);
#pragma unroll
    for (int nf = 0; nf < 4; nf++) {
      const char* kr = K_ + (nf * 16 + lrow) * 128;
      bf16x8 bk0 = *(const bf16x8*)(kr + ((16 * lk) ^ sw));
      bf16x8 bk1 = *(const bf16x8*)(kr + ((64 + 16 * lk) ^ sw));
#pragma unroll
      for (int qf = 0; qf < 2; qf++) {
        f32x4 z = {};
        z = __builtin_amdgcn_mfma_f32_16x16x32_bf16(bk0, aq[qf][0], z, 0, 0, 0);
        z = __builtin_amdgcn_mfma_f32_16x16x32_bf16(bk1, aq[qf][1], z, 0, 0, 0);
        s4[qf][nf] = z;
      }
    }
    __builtin_amdgcn_s_setprio(0);
    if (t == tl) {
      int qo = (c & 1) * 32;
#pragma unroll
      for (int qf = 0; qf < 2; qf++) {
        int qoff = qo + qf * 16 + lrow;
#pragma unroll
        for (int nf = 0; nf < 4; nf++)
#pragma unroll
          for (int r = 0; r < 4; r++)
            if (nf * 16 + 4 * lk + r > qoff) s4[qf][nf][r] = -1e30f;
      }
    }
    // no-max softmax: p = 2^s (s pre-scaled by log2e/8; bounded), in-lane partial sums
#pragma unroll
    for (int qf = 0; qf < 2; qf++) {
      float ps = 0.f;
#pragma unroll
      for (int nf = 0; nf < 4; nf++)
#pragma unroll
        for (int r = 0; r < 4; r++) {
          float pv = ex2(s4[qf][nf][r]);
          s4[qf][nf][r] = pv;
          ps += pv;
        }
      lp[qf] += ps;
    }
    // PV: o^T[d][q] += V^T * P^T, nf-tiles paired {np, np+2} into one 16x16x32 MFMA
    __builtin_amdgcn_s_setprio(1);
#pragma unroll
    for (int np = 0; np < 2; np++) {
      bf16x8 pb[2];
#pragma unroll
      for (int qf = 0; qf < 2; qf++) {
        uint4 t4;
        t4.x = pkbf(s4[qf][np][0], s4[qf][np][1]);
        t4.y = pkbf(s4[qf][np][2], s4[qf][np][3]);
        t4.z = pkbf(s4[qf][np + 2][0], s4[qf][np + 2][1]);
        t4.w = pkbf(s4[qf][np + 2][2], s4[qf][np + 2][3]);
        pb[qf] = __builtin_bit_cast(bf16x8, t4);
      }
#pragma unroll
      for (int dn = 0; dn < 4; dn++) {
        const char* vr = V_ + (dn * 16 + lrow) * 128;
        uint2 a0 = *(const uint2*)(vr + ((np * 32 + 8 * lk) ^ sw));
        uint2 a1 = *(const uint2*)(vr + (((np + 2) * 32 + 8 * lk) ^ sw));
        uint4 av;
        av.x = a0.x; av.y = a0.y; av.z = a1.x; av.w = a1.y;
        bf16x8 va = __builtin_bit_cast(bf16x8, av);
#pragma unroll
        for (int qf = 0; qf < 2; qf++)
          o[qf][dn] = __builtin_amdgcn_mfma_f32_16x16x32_bf16(va, pb[qf], o[qf][dn], 0, 0, 0);
      }
    }
    __builtin_amdgcn_s_setprio(0);
  }
  // epilogue: reduce lp across the 4 lk-lanes of each q-row, normalize, store b64 packs
#pragma unroll
  for (int qf = 0; qf < 2; qf++) {
    float s = lp[qf];
    s += __shfl_xor(s, 16);
    s += __shfl_xor(s, 32);
    float inv = 1.f / s;
    int qrow = c * 32 + qf * 16 + lrow;
    __bf16* op = O + (size_t)(b * 2048 + qrow) * 2048 + h * 64 + 4 * lk;
#pragma unroll
    for (int dn = 0; dn < 4; dn++) {
      bf16x4 stv;
#pragma unroll
      for (int r = 0; r < 4; r++) stv[r] = (__bf16)(o[qf][dn][r] * inv);
      *(bf16x4*)(op + dn * 16) = stv;
    }
  }
#undef STAGE
}

extern "C" void kernel_launch(void* const* d_in, const int* in_sizes, int n_in,
                              void* d_out, int out_size, void* d_ws, size_t ws_size,
                              hipStream_t stream) {
  const float* x = (const float*)d_in[0];
  const float* wq = (const float*)d_in[1];
  const float* wk = (const float*)d_in[2];
  const float* wv = (const float*)d_in[3];
  const float* wo = (const float*)d_in[4];
  char* ws = (char*)d_ws;
  __bf16* xb    = (__bf16*)(ws + 0);          // 16,777,216
  __bf16* wqkvT = (__bf16*)(ws + 16777216);   // 12,582,912  [3072][2048]
  __bf16* woT   = (__bf16*)(ws + 29360128);   //  8,388,608
  __bf16* qb    = (__bf16*)(ws + 37748736);   // 16,777,216
  __bf16* kb    = (__bf16*)(ws + 54525952);   //  4,194,304
  __bf16* vt    = (__bf16*)(ws + 58720256);   //  4,194,304
  __bf16* ob    = (__bf16*)(ws + 62914560);   // 16,777,216
  float*  ct    = (float*)(ws + 79691776);    //    262,144
  float*  st    = (float*)(ws + 79953920);    //    262,144
  float* out = (float*)d_out;

  // prep: cvt + wq/wk/wv transpose-convert + rope table (wo transpose deferred)
  k_prep<<<10496, 256, 0, stream>>>(x, xb, wq, wk, wv, wqkvT, ct, st);
  // QKV: round-1 structure, grid 16x16 = 256 blocks -> every CU gets one block.
  k_gemm256<192, 12, 3, 0><<<256, 768, 0, stream>>>(xb, wqkvT, qb, kb, vt, ct, st, 2048, 16);
  // attn (blocks 0..1023, descending-c) + deferred wo transpose tail-fill (1024..5119).
  k_attn<<<5120, 256, 0, stream>>>(qb, kb, vt, ob, wo, woT);
  // WO: round-2 structure (3-deep A pipeline + XCD swizzle), measured faster for MODE 1.
  k_gemm3d<128, 8, 2, 1><<<256, 512, 0, stream>>>(ob, woT, out, 2048, 16);
}